// Round 6
// baseline (1013.154 us; speedup 1.0000x reference)
//
#include <hip/hip_runtime.h>

#define LSEQ   4096
#define EMBED  1024
#define NHEADS 16
#define HDIM   64
#define QKV_N  3072

typedef __attribute__((ext_vector_type(8))) short bf16x8;
typedef __attribute__((ext_vector_type(4))) float f32x4;

// round-to-nearest-even fp32 -> bf16 (bit pattern), no header dependence
__device__ inline unsigned short bf16_rne(float x) {
    unsigned int u = __float_as_uint(x);
    unsigned int r = (u + 0x7fffu + ((u >> 16) & 1u)) >> 16;
    return (unsigned short)r;
}
__device__ inline float bf16_to_f32(unsigned short h) {
    return __uint_as_float(((unsigned int)h) << 16);
}

// ---------------------------------------------------------------------------
// Convert contiguous fp32 -> hi/lo bf16 arrays. n multiple of 1024.
// ---------------------------------------------------------------------------
__global__ __launch_bounds__(256)
void convert_hilo(const float* __restrict__ in, unsigned short* __restrict__ hi,
                  unsigned short* __restrict__ lo, int n)
{
    int i = (blockIdx.x * 256 + threadIdx.x) << 2;
    if (i >= n) return;
    float4 v = *reinterpret_cast<const float4*>(&in[i]);
    float a[4] = {v.x, v.y, v.z, v.w};
    unsigned short hh[4], ll[4];
    #pragma unroll
    for (int j = 0; j < 4; ++j) {
        hh[j] = bf16_rne(a[j]);
        ll[j] = bf16_rne(a[j] - bf16_to_f32(hh[j]));
    }
    *reinterpret_cast<ushort4*>(&hi[i]) = make_ushort4(hh[0], hh[1], hh[2], hh[3]);
    *reinterpret_cast<ushort4*>(&lo[i]) = make_ushort4(ll[0], ll[1], ll[2], ll[3]);
}

// ---------------------------------------------------------------------------
// Convert fp32 W[K][N] -> TRANSPOSED hi/lo bf16 Wt[N][K] (for B-operand).
// 64x64 LDS tile transpose. K,N multiples of 64.
// ---------------------------------------------------------------------------
__global__ __launch_bounds__(256)
void convert_T_hilo(const float* __restrict__ in, unsigned short* __restrict__ hi,
                    unsigned short* __restrict__ lo, int K, int N)
{
    __shared__ float tile[64][65];
    const int n0 = blockIdx.x * 64, k0 = blockIdx.y * 64;
    const int t = threadIdx.x;
    #pragma unroll
    for (int i = 0; i < 16; ++i) {
        int idx = t + i * 256;           // 0..4095
        int r = idx >> 6, c = idx & 63;  // k-local, n-local
        tile[r][c] = in[(size_t)(k0 + r) * N + n0 + c];
    }
    __syncthreads();
    #pragma unroll
    for (int i = 0; i < 16; ++i) {
        int idx = t + i * 256;
        int r = idx >> 6, c = idx & 63;  // n-local, k-local
        float v = tile[c][r];
        unsigned short h = bf16_rne(v);
        unsigned short l = bf16_rne(v - bf16_to_f32(h));
        size_t o = (size_t)(n0 + r) * K + k0 + c;
        hi[o] = h;
        lo[o] = l;
    }
}

// ---------------------------------------------------------------------------
// bf16x3 split GEMM v4: C = A @ B^T_stored + bias (logical C = A @ B + bias)
// A_hi/A_lo: [M][K] bf16 (lda=K). Bt_hi/Bt_lo: [N][K] bf16 (ldb=K). C fp32.
// 64x64 tile (grid 2x vs v3 -> ~4 waves/SIMD), BK=32, 4 waves, each wave
// owns a 32x32 output sub-tile (2x2 frags, 12 MFMA / 8 ds_read per K-step).
// Double-buffered 1-ahead prefetch via global_load_lds(16B), XOR-swizzled
// tiles (16B chunk c -> c ^ ((row>>1)&3)) on source addr + frag reads.
// LDS 32 KB. M, N multiples of 64; K multiple of 32.
// ---------------------------------------------------------------------------
__global__ __launch_bounds__(256)
void gemm3_kernel(const unsigned short* __restrict__ Ah, const unsigned short* __restrict__ Al,
                  const unsigned short* __restrict__ Bh, const unsigned short* __restrict__ Bl,
                  const float* __restrict__ bias, float* __restrict__ C,
                  int K, int ldc)
{
    // shorts: Ah[64][32] @0, Al @2048, Bh @4096, Bl @6144 ; x2 buffers = 32 KB
    __shared__ __align__(16) unsigned short lds[2][8192];

    const int t = threadIdx.x;
    const int wave = t >> 6, lane = t & 63;
    const int wr = wave >> 1, wc = wave & 1;     // wave tile: 32 rows x 32 cols
    const int rowBase = blockIdx.y * 64;
    const int colBase = blockIdx.x * 64;
    const int fr = lane & 15, fq = lane >> 4;

    // staging: wave w stages tile w (Ah/Al/Bh/Bl), 4 issues x 64 lanes x 16B
    const unsigned short* src = (wave == 0) ? Ah : (wave == 1) ? Al : (wave == 2) ? Bh : Bl;
    const int tileRow0 = (wave < 2) ? rowBase : colBase;
    const int ldsOff = wave * 2048;
    const int sRow = lane >> 2;                                  // 0..15
    const int sChunk = (((lane & 3) ^ ((lane >> 3) & 3)) << 3);  // swizzled k-chunk (elems)

    f32x4 acc[2][2] = {};
    const int NT = K >> 5;

    // prologue: stage tile 0 into buffer 0
    #pragma unroll
    for (int i = 0; i < 4; ++i) {
        const unsigned short* g = src + (size_t)(tileRow0 + i * 16 + sRow) * K + sChunk;
        __builtin_amdgcn_global_load_lds(
            (const __attribute__((address_space(1))) void*)g,
            (__attribute__((address_space(3))) void*)&lds[0][ldsOff + i * 512], 16, 0, 0);
    }
    __syncthreads();

    for (int tI = 0; tI < NT; ++tI) {
        const int cur = tI & 1;

        // prefetch next K-tile into the other buffer (in flight across MFMA phase)
        if (tI + 1 < NT) {
            const int k0 = (tI + 1) << 5;
            #pragma unroll
            for (int i = 0; i < 4; ++i) {
                const unsigned short* g =
                    src + (size_t)(tileRow0 + i * 16 + sRow) * K + k0 + sChunk;
                __builtin_amdgcn_global_load_lds(
                    (const __attribute__((address_space(1))) void*)g,
                    (__attribute__((address_space(3))) void*)&lds[cur ^ 1][ldsOff + i * 512], 16, 0, 0);
            }
        }

        // fragment reads (swizzled) + MFMA
        bf16x8 ah[2], al[2], bh[2], bl[2];
        #pragma unroll
        for (int m = 0; m < 2; ++m) {
            int r = wr * 32 + m * 16 + fr;
            int off = r * 32 + ((fq ^ ((r >> 1) & 3)) << 3);
            ah[m] = *reinterpret_cast<const bf16x8*>(&lds[cur][off]);
            al[m] = *reinterpret_cast<const bf16x8*>(&lds[cur][2048 + off]);
        }
        #pragma unroll
        for (int n = 0; n < 2; ++n) {
            int r = wc * 32 + n * 16 + fr;
            int off = r * 32 + ((fq ^ ((r >> 1) & 3)) << 3);
            bh[n] = *reinterpret_cast<const bf16x8*>(&lds[cur][4096 + off]);
            bl[n] = *reinterpret_cast<const bf16x8*>(&lds[cur][6144 + off]);
        }
        #pragma unroll
        for (int m = 0; m < 2; ++m)
            #pragma unroll
            for (int n = 0; n < 2; ++n) {
                acc[m][n] = __builtin_amdgcn_mfma_f32_16x16x32_bf16(ah[m], bh[n], acc[m][n], 0, 0, 0);
                acc[m][n] = __builtin_amdgcn_mfma_f32_16x16x32_bf16(ah[m], bl[n], acc[m][n], 0, 0, 0);
                acc[m][n] = __builtin_amdgcn_mfma_f32_16x16x32_bf16(al[m], bh[n], acc[m][n], 0, 0, 0);
            }

        __syncthreads();  // drains this iter's prefetch (overlapped with MFMA above)
    }

    // epilogue: C/D frag mapping col=lane&15, row=(lane>>4)*4+reg (m89-verified)
    #pragma unroll
    for (int m = 0; m < 2; ++m) {
        #pragma unroll
        for (int n = 0; n < 2; ++n) {
            int col = colBase + wc * 32 + n * 16 + fr;
            float bv = bias[col];
            #pragma unroll
            for (int r = 0; r < 4; ++r) {
                int row = rowBase + wr * 32 + m * 16 + fq * 4 + r;
                C[(size_t)row * ldc + col] = acc[m][n][r] + bv;
            }
        }
    }
}

// ---------------------------------------------------------------------------
// kv partial v2: per (128-row chunk, head, m-half) for ONE L-half (2048 rows).
// grid (16, 16, 2) = 512 blocks. kvb: [2048][2048] fp32 (k at col h*64,
// v at col 1024+h*64). Each block computes k'[:, mh*32:+32] = relu(RoPE(k)
// @ proj[h][:, mh*32:+32]) * mask and accumulates kv[mh*32:+32][all d], ksum.
// partial layout: [h][16 chunks][4160] (4096 = kv [m][d], +64 = ksum);
// the two mh blocks write disjoint halves. first=1 -> overwrite partials.
// ---------------------------------------------------------------------------
__global__ __launch_bounds__(256)
void kv_partial_kernel(const float* __restrict__ kvb, const float* __restrict__ cosb,
                       const float* __restrict__ sinb, const float* __restrict__ maskb,
                       const float* __restrict__ proj, float* __restrict__ partial,
                       int first)
{
    const int chunk = blockIdx.x;   // 0..15 (128 rows each)
    const int h     = blockIdx.y;   // 0..15
    const int mh    = blockIdx.z;   // 0..1 (m-half)
    const int t = threadIdx.x;

    __shared__ float bufA[64][68];  // k_rot, then v (reused)
    __shared__ float kp[64][36];    // k' half: 32 m cols (+4 pad)
    __shared__ float pj[64][32];    // proj[h][d][mh*32 .. +32]

    // load proj column-half: 2048 floats = 512 float4
    for (int i = t; i < 512; i += 256) {
        int d = i >> 3, c4 = (i & 7) << 2;
        *reinterpret_cast<float4*>(&pj[d][c4]) =
            *reinterpret_cast<const float4*>(&proj[(size_t)h * 4096 + d * 64 + mh * 32 + c4]);
    }

    const int am  = t >> 3;         // 0..31 local m
    const int ad0 = (t & 7) << 3;   // d start: 0,8,..,56
    float acc[8] = {};
    float ks = 0.f;

    for (int sub = 0; sub < 2; ++sub) {
        const int rowL = chunk * 128 + sub * 64;
        __syncthreads();

        // RoPE-load K tile: 64 rows x 32 pairs
        #pragma unroll
        for (int i = 0; i < 8; ++i) {
            int p = t + i * 256;
            int l = p >> 5, i2 = p & 31;
            size_t base = (size_t)(rowL + l) * 2048 + h * HDIM + 2 * i2;
            float kr = kvb[base], ki = kvb[base + 1];
            float c = cosb[(size_t)(rowL + l) * 32 + i2];
            float s = sinb[(size_t)(rowL + l) * 32 + i2];
            bufA[l][2 * i2]     = kr * c - ki * s;
            bufA[l][2 * i2 + 1] = kr * s + ki * c;
        }
        __syncthreads();

        // k'half = relu(k_rot @ pj) * mask : 64 l rows x 32 m cols
        {
            int l = t >> 2, m0 = (t & 3) << 3;     // 8 m per thread
            float a[8] = {};
            for (int d = 0; d < 64; ++d) {
                float kl = bufA[l][d];
                const float* pr = &pj[d][m0];
                #pragma unroll
                for (int j = 0; j < 8; ++j) a[j] = fmaf(kl, pr[j], a[j]);
            }
            float mv = maskb[rowL + l];
            #pragma unroll
            for (int j = 0; j < 8; ++j) kp[l][m0 + j] = fmaxf(a[j], 0.f) * mv;
        }
        __syncthreads();

        // load masked V into bufA
        #pragma unroll
        for (int i = 0; i < 4; ++i) {
            int idx = t + i * 256;
            int l = idx >> 4, dd = (idx & 15) << 2;
            float4 v = *reinterpret_cast<const float4*>(
                &kvb[(size_t)(rowL + l) * 2048 + 1024 + h * HDIM + dd]);
            float mv = maskb[rowL + l];
            v.x *= mv; v.y *= mv; v.z *= mv; v.w *= mv;
            *reinterpret_cast<float4*>(&bufA[l][dd]) = v;
        }
        __syncthreads();

        // accumulate kv[am][ad0..+8] and ksum[am]
        for (int l = 0; l < 64; ++l) {
            float kl = kp[l][am];
            ks += kl;
            const float* vr = &bufA[l][ad0];
            #pragma unroll
            for (int j = 0; j < 8; ++j) acc[j] = fmaf(kl, vr[j], acc[j]);
        }
    }

    float* dst = partial + ((size_t)h * 16 + chunk) * 4160;
    const int mrow = mh * 32 + am;
    if (first) {
        #pragma unroll
        for (int j4 = 0; j4 < 2; ++j4) {
            float4 o = {acc[j4 * 4 + 0], acc[j4 * 4 + 1], acc[j4 * 4 + 2], acc[j4 * 4 + 3]};
            *reinterpret_cast<float4*>(&dst[mrow * 64 + ad0 + j4 * 4]) = o;
        }
        if ((t & 7) == 0) dst[4096 + mrow] = ks;
    } else {
        #pragma unroll
        for (int j4 = 0; j4 < 2; ++j4) {
            float4 p = *reinterpret_cast<const float4*>(&dst[mrow * 64 + ad0 + j4 * 4]);
            float4 o = {p.x + acc[j4 * 4 + 0], p.y + acc[j4 * 4 + 1],
                        p.z + acc[j4 * 4 + 2], p.w + acc[j4 * 4 + 3]};
            *reinterpret_cast<float4*>(&dst[mrow * 64 + ad0 + j4 * 4]) = o;
        }
        if ((t & 7) == 0) dst[4096 + mrow] += ks;
    }
}

// Reduce 16 chunk partials -> kv (64x64) + ksum (64) per head. grid (16,4).
__global__ __launch_bounds__(256)
void kv_reduce_kernel(const float* __restrict__ partial, float* __restrict__ kvout)
{
    const int h = blockIdx.x;
    const int seg = blockIdx.y;           // 4160 = 4 segments x 1040
    for (int idx = seg * 1040 + threadIdx.x; idx < (seg + 1) * 1040; idx += 256) {
        float s = 0.f;
        for (int c = 0; c < 16; ++c)
            s += partial[((size_t)h * 16 + c) * 4160 + idx];
        kvout[(size_t)h * 4160 + idx] = s;
    }
}

// ---------------------------------------------------------------------------
// context per (h, 64-row L tile) for ONE batch:
// RoPE(q) -> q' = relu(q_rot @ proj[h]) -> ctx = (q' @ kv) / (q'.ksum + 1e-4)
// qb: [4096][1024] (q at col h*64). Writes ctx directly as hi/lo bf16.
// ---------------------------------------------------------------------------
__global__ __launch_bounds__(256)
void context_kernel(const float* __restrict__ qb, const float* __restrict__ cosb,
                    const float* __restrict__ sinb, const float* __restrict__ proj,
                    const float* __restrict__ kvsum, unsigned short* __restrict__ ch,
                    unsigned short* __restrict__ cl)
{
    const int lt = blockIdx.x;   // 0..63
    const int h  = blockIdx.y;   // 0..15
    const int t = threadIdx.x;

    __shared__ float bufA[64][68];  // q_rot, then reused for kv
    __shared__ float qp[64][68];    // q'
    __shared__ float pj[64][64];
    __shared__ float ksum[64];

    for (int i = t; i < 1024; i += 256)
        *reinterpret_cast<float4*>(&pj[0][0] + (size_t)i * 4) =
            *reinterpret_cast<const float4*>(proj + (size_t)h * 4096 + (size_t)i * 4);
    if (t < 64) ksum[t] = kvsum[(size_t)h * 4160 + 4096 + t];

    const int rowL = lt * 64;
    #pragma unroll
    for (int i = 0; i < 8; ++i) {
        int p = t + i * 256;
        int l = p >> 5, i2 = p & 31;
        size_t base = (size_t)(rowL + l) * 1024 + h * HDIM + 2 * i2;
        float qr = qb[base], qi = qb[base + 1];
        float c = cosb[(size_t)(rowL + l) * 32 + i2];
        float s = sinb[(size_t)(rowL + l) * 32 + i2];
        bufA[l][2 * i2]     = qr * c - qi * s;
        bufA[l][2 * i2 + 1] = qr * s + qi * c;
    }
    __syncthreads();

    {
        int l = t >> 2, m0 = (t & 3) << 4;
        float a[16] = {};
        for (int d = 0; d < 64; ++d) {
            float ql = bufA[l][d];
            const float* pr = &pj[d][m0];
            #pragma unroll
            for (int j = 0; j < 16; ++j) a[j] = fmaf(ql, pr[j], a[j]);
        }
        #pragma unroll
        for (int j = 0; j < 16; ++j) qp[l][m0 + j] = fmaxf(a[j], 0.f);
    }
    __syncthreads();

    #pragma unroll
    for (int i = 0; i < 4; ++i) {
        int idx = t + i * 256;
        int mm = idx >> 4, dd = (idx & 15) << 2;
        *reinterpret_cast<float4*>(&bufA[mm][dd]) =
            *reinterpret_cast<const float4*>(&kvsum[(size_t)h * 4160 + mm * 64 + dd]);
    }
    __syncthreads();

    {
        int l = t >> 2, d0 = (t & 3) << 4;
        float a[16] = {};
        float nrm = 0.f;
        for (int mm = 0; mm < 64; ++mm) {
            float qv = qp[l][mm];
            nrm = fmaf(qv, ksum[mm], nrm);
            const float* kr = &bufA[mm][d0];
            #pragma unroll
            for (int j = 0; j < 16; ++j) a[j] = fmaf(qv, kr[j], a[j]);
        }
        float inv = 1.0f / (nrm + 1e-4f);
        size_t orow = (size_t)(rowL + l) * 1024 + h * HDIM + d0;
        #pragma unroll
        for (int j4 = 0; j4 < 4; ++j4) {
            unsigned short hh[4], ll[4];
            #pragma unroll
            for (int j = 0; j < 4; ++j) {
                float v = a[j4 * 4 + j] * inv;
                hh[j] = bf16_rne(v);
                ll[j] = bf16_rne(v - bf16_to_f32(hh[j]));
            }
            *reinterpret_cast<ushort4*>(&ch[orow + j4 * 4]) = make_ushort4(hh[0], hh[1], hh[2], hh[3]);
            *reinterpret_cast<ushort4*>(&cl[orow + j4 * 4]) = make_ushort4(ll[0], ll[1], ll[2], ll[3]);
        }
    }
}

extern "C" void kernel_launch(void* const* d_in, const int* in_sizes, int n_in,
                              void* d_out, int out_size, void* d_ws, size_t ws_size,
                              hipStream_t stream)
{
    const float* x    = (const float*)d_in[0];
    const float* fcos = (const float*)d_in[1];
    const float* fsin = (const float*)d_in[2];
    const float* mask = (const float*)d_in[3];
    const float* Wqkv = (const float*)d_in[4];
    const float* bqkv = (const float*)d_in[5];
    const float* proj = (const float*)d_in[6];
    const float* Wout = (const float*)d_in[7];
    const float* bout = (const float*)d_in[8];
    float* out = (float*)d_out;

    // Workspace (floats), 13,714,432 fl = 54.86 MB (== round-2 proven size):
    float* R0 = (float*)d_ws;          // KV-half fp32 [2048][2048] / q fp32 [4096][1024]
    float* R1 = R0 + 4194304;          // x hi+lo bf16 / ctx hi+lo bf16
    float* R2 = R1 + 4194304;          // weights hi/lo (persistent, transposed)
    float* R3 = R2 + 4194304;          // partials [16][16][4160] = 1,064,960
    float* R4 = R3 + 1064960;          // kvsum [16][4160] = 66,560

    unsigned short* xh  = (unsigned short*)R1;      // also ctx hi (x dead by then)
    unsigned short* xl  = xh + 4194304;             // also ctx lo
    unsigned short* Wqh = (unsigned short*)R2;      // Wqkv^T hi: [3072][1024]
    unsigned short* Wql = Wqh + 3145728;
    unsigned short* Woh = Wql + 3145728;            // Wout^T hi: [1024][1024]
    unsigned short* Wol = Woh + 1048576;

    // Weight conversions (once per launch), transposed for B-operand K-contiguity
    convert_T_hilo<<<dim3(3072 / 64, 1024 / 64), 256, 0, stream>>>(Wqkv, Wqh, Wql, 1024, 3072);
    convert_T_hilo<<<dim3(1024 / 64, 1024 / 64), 256, 0, stream>>>(Wout, Woh, Wol, 1024, 1024);

    for (int b = 0; b < 4; ++b) {
        const float* xb = x + (size_t)b * 4194304;

        convert_hilo<<<4096, 256, 0, stream>>>(xb, xh, xl, 4194304);

        // K,V in two L-halves; kv partials accumulate across halves
        for (int half = 0; half < 2; ++half) {
            gemm3_kernel<<<dim3(2048 / 64, 2048 / 64), 256, 0, stream>>>(
                xh + (size_t)half * 2048 * 1024, xl + (size_t)half * 2048 * 1024,
                Wqh + (size_t)1024 * 1024, Wql + (size_t)1024 * 1024,
                bqkv + 1024, R0, 1024, 2048);
            kv_partial_kernel<<<dim3(16, 16, 2), 256, 0, stream>>>(
                R0, fcos + (size_t)half * 2048 * 32, fsin + (size_t)half * 2048 * 32,
                mask + (size_t)b * 4096 + half * 2048, proj, R3, half == 0 ? 1 : 0);
        }
        kv_reduce_kernel<<<dim3(16, 4), 256, 0, stream>>>(R3, R4);

        // Q (full 4096 rows) -> R0
        gemm3_kernel<<<dim3(1024 / 64, 4096 / 64), 256, 0, stream>>>(
            xh, xl, Wqh, Wql, bqkv, R0, 1024, 1024);

        // context + normalization (fused RoPE + proj + relu + hi/lo split on Q)
        context_kernel<<<dim3(64, 16), 256, 0, stream>>>(
            R0, fcos, fsin, proj, R4, xh, xl);

        // out_b = ctx @ Wout + bout
        gemm3_kernel<<<dim3(1024 / 64, 4096 / 64), 256, 0, stream>>>(
            xh, xl, Woh, Wol, bout, out + (size_t)b * 4194304, 1024, 1024);
    }
}

// Round 7
// 899.281 us; speedup vs baseline: 1.1266x; 1.1266x over previous
//
#include <hip/hip_runtime.h>

#define LSEQ   4096
#define EMBED  1024
#define NHEADS 16
#define HDIM   64
#define QKV_N  3072

typedef __attribute__((ext_vector_type(8))) short bf16x8;
typedef __attribute__((ext_vector_type(8))) unsigned short u16x8;
typedef __attribute__((ext_vector_type(4))) float f32x4;

// round-to-nearest-even fp32 -> bf16 (bit pattern), no header dependence
__device__ inline unsigned short bf16_rne(float x) {
    unsigned int u = __float_as_uint(x);
    unsigned int r = (u + 0x7fffu + ((u >> 16) & 1u)) >> 16;
    return (unsigned short)r;
}
__device__ inline float bf16_to_f32(unsigned short h) {
    return __uint_as_float(((unsigned int)h) << 16);
}

// swizzled short-index into a [64 rows][64 shorts] LDS tile:
// 16B chunk c of row r lives at chunk c ^ (r & 7) -> conflict-free b128
// column reads at stride 128B with no padding.
__device__ __forceinline__ int swz64(int row, int s) {
    return row * 64 + ((((s >> 3) ^ (row & 7))) << 3) + (s & 7);
}

// ---------------------------------------------------------------------------
// Convert contiguous fp32 -> hi/lo bf16 arrays. n multiple of 1024.
// ---------------------------------------------------------------------------
__global__ __launch_bounds__(256)
void convert_hilo(const float* __restrict__ in, unsigned short* __restrict__ hi,
                  unsigned short* __restrict__ lo, int n)
{
    int i = (blockIdx.x * 256 + threadIdx.x) << 2;
    if (i >= n) return;
    float4 v = *reinterpret_cast<const float4*>(&in[i]);
    float a[4] = {v.x, v.y, v.z, v.w};
    unsigned short hh[4], ll[4];
    #pragma unroll
    for (int j = 0; j < 4; ++j) {
        hh[j] = bf16_rne(a[j]);
        ll[j] = bf16_rne(a[j] - bf16_to_f32(hh[j]));
    }
    *reinterpret_cast<ushort4*>(&hi[i]) = make_ushort4(hh[0], hh[1], hh[2], hh[3]);
    *reinterpret_cast<ushort4*>(&lo[i]) = make_ushort4(ll[0], ll[1], ll[2], ll[3]);
}

// ---------------------------------------------------------------------------
// Convert fp32 W[K][N] -> TRANSPOSED hi/lo bf16 Wt[N][K] (for B-operand).
// ---------------------------------------------------------------------------
__global__ __launch_bounds__(256)
void convert_T_hilo(const float* __restrict__ in, unsigned short* __restrict__ hi,
                    unsigned short* __restrict__ lo, int K, int N)
{
    __shared__ float tile[64][65];
    const int n0 = blockIdx.x * 64, k0 = blockIdx.y * 64;
    const int t = threadIdx.x;
    #pragma unroll
    for (int i = 0; i < 16; ++i) {
        int idx = t + i * 256;
        int r = idx >> 6, c = idx & 63;
        tile[r][c] = in[(size_t)(k0 + r) * N + n0 + c];
    }
    __syncthreads();
    #pragma unroll
    for (int i = 0; i < 16; ++i) {
        int idx = t + i * 256;
        int r = idx >> 6, c = idx & 63;
        float v = tile[c][r];
        unsigned short h = bf16_rne(v);
        unsigned short l = bf16_rne(v - bf16_to_f32(h));
        size_t o = (size_t)(n0 + r) * K + k0 + c;
        hi[o] = h;
        lo[o] = l;
    }
}

// ---------------------------------------------------------------------------
// bf16x3 split GEMM v4 (unchanged from R6): C = A @ B^T_stored + bias.
// 64x64 tile, BK=32, 4 waves, 2x2 frags/wave. Dbuf prefetch + XOR swizzle.
// ---------------------------------------------------------------------------
__global__ __launch_bounds__(256)
void gemm3_kernel(const unsigned short* __restrict__ Ah, const unsigned short* __restrict__ Al,
                  const unsigned short* __restrict__ Bh, const unsigned short* __restrict__ Bl,
                  const float* __restrict__ bias, float* __restrict__ C,
                  int K, int ldc)
{
    __shared__ __align__(16) unsigned short lds[2][8192];

    const int t = threadIdx.x;
    const int wave = t >> 6, lane = t & 63;
    const int wr = wave >> 1, wc = wave & 1;
    const int rowBase = blockIdx.y * 64;
    const int colBase = blockIdx.x * 64;
    const int fr = lane & 15, fq = lane >> 4;

    const unsigned short* src = (wave == 0) ? Ah : (wave == 1) ? Al : (wave == 2) ? Bh : Bl;
    const int tileRow0 = (wave < 2) ? rowBase : colBase;
    const int ldsOff = wave * 2048;
    const int sRow = lane >> 2;
    const int sChunk = (((lane & 3) ^ ((lane >> 3) & 3)) << 3);

    f32x4 acc[2][2] = {};
    const int NT = K >> 5;

    #pragma unroll
    for (int i = 0; i < 4; ++i) {
        const unsigned short* g = src + (size_t)(tileRow0 + i * 16 + sRow) * K + sChunk;
        __builtin_amdgcn_global_load_lds(
            (const __attribute__((address_space(1))) void*)g,
            (__attribute__((address_space(3))) void*)&lds[0][ldsOff + i * 512], 16, 0, 0);
    }
    __syncthreads();

    for (int tI = 0; tI < NT; ++tI) {
        const int cur = tI & 1;
        if (tI + 1 < NT) {
            const int k0 = (tI + 1) << 5;
            #pragma unroll
            for (int i = 0; i < 4; ++i) {
                const unsigned short* g =
                    src + (size_t)(tileRow0 + i * 16 + sRow) * K + k0 + sChunk;
                __builtin_amdgcn_global_load_lds(
                    (const __attribute__((address_space(1))) void*)g,
                    (__attribute__((address_space(3))) void*)&lds[cur ^ 1][ldsOff + i * 512], 16, 0, 0);
            }
        }

        bf16x8 ah[2], al[2], bh[2], bl[2];
        #pragma unroll
        for (int m = 0; m < 2; ++m) {
            int r = wr * 32 + m * 16 + fr;
            int off = r * 32 + ((fq ^ ((r >> 1) & 3)) << 3);
            ah[m] = *reinterpret_cast<const bf16x8*>(&lds[cur][off]);
            al[m] = *reinterpret_cast<const bf16x8*>(&lds[cur][2048 + off]);
        }
        #pragma unroll
        for (int n = 0; n < 2; ++n) {
            int r = wc * 32 + n * 16 + fr;
            int off = r * 32 + ((fq ^ ((r >> 1) & 3)) << 3);
            bh[n] = *reinterpret_cast<const bf16x8*>(&lds[cur][4096 + off]);
            bl[n] = *reinterpret_cast<const bf16x8*>(&lds[cur][6144 + off]);
        }
        #pragma unroll
        for (int m = 0; m < 2; ++m)
            #pragma unroll
            for (int n = 0; n < 2; ++n) {
                acc[m][n] = __builtin_amdgcn_mfma_f32_16x16x32_bf16(ah[m], bh[n], acc[m][n], 0, 0, 0);
                acc[m][n] = __builtin_amdgcn_mfma_f32_16x16x32_bf16(ah[m], bl[n], acc[m][n], 0, 0, 0);
                acc[m][n] = __builtin_amdgcn_mfma_f32_16x16x32_bf16(al[m], bh[n], acc[m][n], 0, 0, 0);
            }
        __syncthreads();
    }

    #pragma unroll
    for (int m = 0; m < 2; ++m) {
        #pragma unroll
        for (int n = 0; n < 2; ++n) {
            int col = colBase + wc * 32 + n * 16 + fr;
            float bv = bias[col];
            #pragma unroll
            for (int r = 0; r < 4; ++r) {
                int row = rowBase + wr * 32 + m * 16 + fq * 4 + r;
                C[(size_t)row * ldc + col] = acc[m][n][r] + bv;
            }
        }
    }
}

// ---------------------------------------------------------------------------
// kv MFMA kernel: per (chunk of 128 L-rows, head) for ONE L-half.
// Fuses: RoPE(k)->split -> MFMA1 k'=krot@proj^T -> relu*mask -> split ->
// transposed KPT -> MFMA2 kv += k'^T (v*mask), ksum via shfl reduce.
// partial layout: [h][16 chunks][4160] (4096 = kv [m][d], +64 = ksum).
// All LDS tiles [64][64] shorts with chunk-XOR swizzle (swz64).
// ---------------------------------------------------------------------------
__global__ __launch_bounds__(256)
void kv_mfma_kernel(const float* __restrict__ kvb, const float* __restrict__ cosb,
                    const float* __restrict__ sinb, const float* __restrict__ maskb,
                    const float* __restrict__ proj, float* __restrict__ partial,
                    int first)
{
    // LDS: 0: KR_h(8K) 8192: KR_l(8K)  [aliased: PS/VS fp32 [64][64] 16K]
    // 16384: PJT_h 24576: PJT_l  32768: KPT_h 40960: KPT_l
    // 49152: VT_h 57344: VT_l  65536: MS f32[64]  65792: KS f32[4][64]
    __shared__ __align__(16) char smem[66816];
    unsigned short* KR_h  = (unsigned short*)smem;
    unsigned short* KR_l  = (unsigned short*)(smem + 8192);
    float*          PS    = (float*)smem;                    // aliases KR (fp32 [64][64])
    unsigned short* PJT_h = (unsigned short*)(smem + 16384);
    unsigned short* PJT_l = (unsigned short*)(smem + 24576);
    unsigned short* KPT_h = (unsigned short*)(smem + 32768);
    unsigned short* KPT_l = (unsigned short*)(smem + 40960);
    unsigned short* VT_h  = (unsigned short*)(smem + 49152);
    unsigned short* VT_l  = (unsigned short*)(smem + 57344);
    float*          MS    = (float*)(smem + 65536);
    float*          KS    = (float*)(smem + 65792);

    const int chunk = blockIdx.x;   // 0..15 (128 rows each)
    const int hh    = blockIdx.y;   // 0..15
    const int t = threadIdx.x;
    const int w = t >> 6, lane = t & 63;
    const int fr = lane & 15, fq = lane >> 4;

    // ---- prologue: PJT = split(proj[hh]^T) via PS fp32 staging
    {
        int r = t >> 2, c0 = (t & 3) << 4;
        #pragma unroll
        for (int k = 0; k < 4; ++k)
            *reinterpret_cast<float4*>(&PS[r * 64 + c0 + k * 4]) =
                *reinterpret_cast<const float4*>(&proj[(size_t)hh * 4096 + r * 64 + c0 + k * 4]);
    }
    __syncthreads();
    {
        int m = t >> 2, d0 = (t & 3) << 4;
        unsigned short hb[16], lb[16];
        #pragma unroll
        for (int j = 0; j < 16; ++j) {
            float v = PS[(d0 + j) * 64 + m];
            hb[j] = bf16_rne(v);
            lb[j] = bf16_rne(v - bf16_to_f32(hb[j]));
        }
        #pragma unroll
        for (int cp = 0; cp < 2; ++cp) {
            u16x8 vh, vl;
            #pragma unroll
            for (int j = 0; j < 8; ++j) { vh[j] = hb[cp * 8 + j]; vl[j] = lb[cp * 8 + j]; }
            int sidx = swz64(m, d0 + cp * 8);
            *reinterpret_cast<u16x8*>(&PJT_h[sidx]) = vh;
            *reinterpret_cast<u16x8*>(&PJT_l[sidx]) = vl;
        }
    }
    __syncthreads();   // PS dead; PJT ready

    f32x4 acc2[4] = {};
    float ksacc[4] = {0.f, 0.f, 0.f, 0.f};

    for (int sub = 0; sub < 2; ++sub) {
        const int rowL = chunk * 128 + sub * 64;

        // ---- phase K: V block -> regs; K block -> RoPE -> split -> KR; mask -> MS
        float4 vv[4];
        {
            int l = t >> 2, c0 = (t & 3) << 4;
            #pragma unroll
            for (int k2 = 0; k2 < 4; ++k2)
                vv[k2] = *reinterpret_cast<const float4*>(
                    &kvb[(size_t)(rowL + l) * 2048 + 1024 + hh * 64 + c0 + k2 * 4]);
        }
        #pragma unroll
        for (int i = 0; i < 8; ++i) {
            int p = t + (i << 8);
            int l = p >> 5, i2 = p & 31;
            size_t base = (size_t)(rowL + l) * 2048 + hh * 64 + 2 * i2;
            float kr = kvb[base], ki = kvb[base + 1];
            float c = cosb[(size_t)(rowL + l) * 32 + i2];
            float s = sinb[(size_t)(rowL + l) * 32 + i2];
            float xr = kr * c - ki * s;
            float xi = kr * s + ki * c;
            unsigned short h0 = bf16_rne(xr), h1 = bf16_rne(xi);
            unsigned short l0 = bf16_rne(xr - bf16_to_f32(h0));
            unsigned short l1 = bf16_rne(xi - bf16_to_f32(h1));
            int sidx = swz64(l, 2 * i2);
            *reinterpret_cast<unsigned int*>(&KR_h[sidx]) = (unsigned)h0 | ((unsigned)h1 << 16);
            *reinterpret_cast<unsigned int*>(&KR_l[sidx]) = (unsigned)l0 | ((unsigned)l1 << 16);
        }
        if (t < 64) MS[t] = maskb[rowL + t];
        __syncthreads();   // B1

        // ---- MFMA1: k' = krot @ proj (K-dim = d = 64, 2 k-steps, x3 split)
        f32x4 acc1[4] = {};
        #pragma unroll
        for (int ks = 0; ks < 2; ++ks) {
            bf16x8 ah = *reinterpret_cast<const bf16x8*>(&KR_h[swz64(16 * w + fr, ks * 32 + fq * 8)]);
            bf16x8 al = *reinterpret_cast<const bf16x8*>(&KR_l[swz64(16 * w + fr, ks * 32 + fq * 8)]);
            #pragma unroll
            for (int n = 0; n < 4; ++n) {
                bf16x8 bh = *reinterpret_cast<const bf16x8*>(&PJT_h[swz64(16 * n + fr, ks * 32 + fq * 8)]);
                bf16x8 bl = *reinterpret_cast<const bf16x8*>(&PJT_l[swz64(16 * n + fr, ks * 32 + fq * 8)]);
                acc1[n] = __builtin_amdgcn_mfma_f32_16x16x32_bf16(ah, bh, acc1[n], 0, 0, 0);
                acc1[n] = __builtin_amdgcn_mfma_f32_16x16x32_bf16(ah, bl, acc1[n], 0, 0, 0);
                acc1[n] = __builtin_amdgcn_mfma_f32_16x16x32_bf16(al, bh, acc1[n], 0, 0, 0);
            }
        }
        // epilogue: relu * mask, split, transposed write KPT[m][l], ksum partials
        #pragma unroll
        for (int n = 0; n < 4; ++n) {
            unsigned short hb[4], lb[4];
            float ssum = 0.f;
            #pragma unroll
            for (int r = 0; r < 4; ++r) {
                int l = 16 * w + fq * 4 + r;
                float kp = fmaxf(acc1[n][r], 0.f) * MS[l];
                ssum += kp;
                hb[r] = bf16_rne(kp);
                lb[r] = bf16_rne(kp - bf16_to_f32(hb[r]));
            }
            ksacc[n] += ssum;
            int sidx = swz64(16 * n + fr, 16 * w + fq * 4);
            *reinterpret_cast<ushort4*>(&KPT_h[sidx]) = make_ushort4(hb[0], hb[1], hb[2], hb[3]);
            *reinterpret_cast<ushort4*>(&KPT_l[sidx]) = make_ushort4(lb[0], lb[1], lb[2], lb[3]);
        }
        __syncthreads();   // B2: MFMA1 reads of KR done -> VS (alias) free

        // ---- VS write (masked V, fp32), from prefetched regs
        {
            float* VS = PS;
            int l = t >> 2, c0 = (t & 3) << 4;
            float mv = MS[l];
            #pragma unroll
            for (int k2 = 0; k2 < 4; ++k2) {
                float4 q = vv[k2];
                q.x *= mv; q.y *= mv; q.z *= mv; q.w *= mv;
                *reinterpret_cast<float4*>(&VS[l * 64 + c0 + k2 * 4]) = q;
            }
        }
        __syncthreads();   // B3

        // ---- VT fill: transpose + split -> VT[d][l]
        {
            float* VS = PS;
            int d = t >> 2, l0 = (t & 3) << 4;
            unsigned short hb[16], lb[16];
            #pragma unroll
            for (int j = 0; j < 16; ++j) {
                float v = VS[(l0 + j) * 64 + d];
                hb[j] = bf16_rne(v);
                lb[j] = bf16_rne(v - bf16_to_f32(hb[j]));
            }
            #pragma unroll
            for (int cp = 0; cp < 2; ++cp) {
                u16x8 vh, vl;
                #pragma unroll
                for (int j = 0; j < 8; ++j) { vh[j] = hb[cp * 8 + j]; vl[j] = lb[cp * 8 + j]; }
                int sidx = swz64(d, l0 + cp * 8);
                *reinterpret_cast<u16x8*>(&VT_h[sidx]) = vh;
                *reinterpret_cast<u16x8*>(&VT_l[sidx]) = vl;
            }
        }
        __syncthreads();   // B4

        // ---- MFMA2: kv += k'^T @ v_masked (K-dim = l = 64, 2 k-steps, x3 split)
        #pragma unroll
        for (int ks = 0; ks < 2; ++ks) {
            bf16x8 ah = *reinterpret_cast<const bf16x8*>(&KPT_h[swz64(16 * w + fr, ks * 32 + fq * 8)]);
            bf16x8 al = *reinterpret_cast<const bf16x8*>(&KPT_l[swz64(16 * w + fr, ks * 32 + fq * 8)]);
            #pragma unroll
            for (int n = 0; n < 4; ++n) {
                bf16x8 bh = *reinterpret_cast<const bf16x8*>(&VT_h[swz64(16 * n + fr, ks * 32 + fq * 8)]);
                bf16x8 bl = *reinterpret_cast<const bf16x8*>(&VT_l[swz64(16 * n + fr, ks * 32 + fq * 8)]);
                acc2[n] = __builtin_amdgcn_mfma_f32_16x16x32_bf16(ah, bh, acc2[n], 0, 0, 0);
                acc2[n] = __builtin_amdgcn_mfma_f32_16x16x32_bf16(ah, bl, acc2[n], 0, 0, 0);
                acc2[n] = __builtin_amdgcn_mfma_f32_16x16x32_bf16(al, bh, acc2[n], 0, 0, 0);
            }
        }
        // no barrier needed here: next sub's writes (KR=VS alias, MS) are not
        // read by MFMA2, and KPT writes happen only after next B1.
    }

    // ---- ksum wave reduce -> KS, then write/accumulate partial
    #pragma unroll
    for (int n = 0; n < 4; ++n) {
        float v = ksacc[n];
        v += __shfl_xor(v, 16);
        v += __shfl_xor(v, 32);
        if (fq == 0) KS[w * 64 + 16 * n + fr] = v;
    }
    __syncthreads();

    float* dst = partial + ((size_t)hh * 16 + chunk) * 4160;
    #pragma unroll
    for (int n = 0; n < 4; ++n)
        #pragma unroll
        for (int r = 0; r < 4; ++r) {
            int m = 16 * w + fq * 4 + r;
            int d = 16 * n + fr;
            if (first) dst[m * 64 + d] = acc2[n][r];
            else       dst[m * 64 + d] += acc2[n][r];
        }
    if (t < 64) {
        float s = KS[t] + KS[64 + t] + KS[128 + t] + KS[192 + t];
        if (first) dst[4096 + t] = s;
        else       dst[4096 + t] += s;
    }
}

// Reduce 16 chunk partials -> kv (64x64) + ksum (64) per head. grid (16,4).
__global__ __launch_bounds__(256)
void kv_reduce_kernel(const float* __restrict__ partial, float* __restrict__ kvout)
{
    const int h = blockIdx.x;
    const int seg = blockIdx.y;           // 4160 = 4 segments x 1040
    for (int idx = seg * 1040 + threadIdx.x; idx < (seg + 1) * 1040; idx += 256) {
        float s = 0.f;
        for (int c = 0; c < 16; ++c)
            s += partial[((size_t)h * 16 + c) * 4160 + idx];
        kvout[(size_t)h * 4160 + idx] = s;
    }
}

// ---------------------------------------------------------------------------
// context per (h, 64-row L tile) for ONE batch (unchanged):
// RoPE(q) -> q' = relu(q_rot @ proj[h]) -> ctx = (q' @ kv) / (q'.ksum + 1e-4)
// Writes ctx directly as hi/lo bf16.
// ---------------------------------------------------------------------------
__global__ __launch_bounds__(256)
void context_kernel(const float* __restrict__ qb, const float* __restrict__ cosb,
                    const float* __restrict__ sinb, const float* __restrict__ proj,
                    const float* __restrict__ kvsum, unsigned short* __restrict__ ch,
                    unsigned short* __restrict__ cl)
{
    const int lt = blockIdx.x;   // 0..63
    const int h  = blockIdx.y;   // 0..15
    const int t = threadIdx.x;

    __shared__ float bufA[64][68];
    __shared__ float qp[64][68];
    __shared__ float pj[64][64];
    __shared__ float ksum[64];

    for (int i = t; i < 1024; i += 256)
        *reinterpret_cast<float4*>(&pj[0][0] + (size_t)i * 4) =
            *reinterpret_cast<const float4*>(proj + (size_t)h * 4096 + (size_t)i * 4);
    if (t < 64) ksum[t] = kvsum[(size_t)h * 4160 + 4096 + t];

    const int rowL = lt * 64;
    #pragma unroll
    for (int i = 0; i < 8; ++i) {
        int p = t + i * 256;
        int l = p >> 5, i2 = p & 31;
        size_t base = (size_t)(rowL + l) * 1024 + h * HDIM + 2 * i2;
        float qr = qb[base], qi = qb[base + 1];
        float c = cosb[(size_t)(rowL + l) * 32 + i2];
        float s = sinb[(size_t)(rowL + l) * 32 + i2];
        bufA[l][2 * i2]     = qr * c - qi * s;
        bufA[l][2 * i2 + 1] = qr * s + qi * c;
    }
    __syncthreads();

    {
        int l = t >> 2, m0 = (t & 3) << 4;
        float a[16] = {};
        for (int d = 0; d < 64; ++d) {
            float ql = bufA[l][d];
            const float* pr = &pj[d][m0];
            #pragma unroll
            for (int j = 0; j < 16; ++j) a[j] = fmaf(ql, pr[j], a[j]);
        }
        #pragma unroll
        for (int j = 0; j < 16; ++j) qp[l][m0 + j] = fmaxf(a[j], 0.f);
    }
    __syncthreads();

    #pragma unroll
    for (int i = 0; i < 4; ++i) {
        int idx = t + i * 256;
        int mm = idx >> 4, dd = (idx & 15) << 2;
        *reinterpret_cast<float4*>(&bufA[mm][dd]) =
            *reinterpret_cast<const float4*>(&kvsum[(size_t)h * 4160 + mm * 64 + dd]);
    }
    __syncthreads();

    {
        int l = t >> 2, d0 = (t & 3) << 4;
        float a[16] = {};
        float nrm = 0.f;
        for (int mm = 0; mm < 64; ++mm) {
            float qv = qp[l][mm];
            nrm = fmaf(qv, ksum[mm], nrm);
            const float* kr = &bufA[mm][d0];
            #pragma unroll
            for (int j = 0; j < 16; ++j) a[j] = fmaf(qv, kr[j], a[j]);
        }
        float inv = 1.0f / (nrm + 1e-4f);
        size_t orow = (size_t)(rowL + l) * 1024 + h * HDIM + d0;
        #pragma unroll
        for (int j4 = 0; j4 < 4; ++j4) {
            unsigned short hh[4], ll[4];
            #pragma unroll
            for (int j = 0; j < 4; ++j) {
                float v = a[j4 * 4 + j] * inv;
                hh[j] = bf16_rne(v);
                ll[j] = bf16_rne(v - bf16_to_f32(hh[j]));
            }
            *reinterpret_cast<ushort4*>(&ch[orow + j4 * 4]) = make_ushort4(hh[0], hh[1], hh[2], hh[3]);
            *reinterpret_cast<ushort4*>(&cl[orow + j4 * 4]) = make_ushort4(ll[0], ll[1], ll[2], ll[3]);
        }
    }
}

extern "C" void kernel_launch(void* const* d_in, const int* in_sizes, int n_in,
                              void* d_out, int out_size, void* d_ws, size_t ws_size,
                              hipStream_t stream)
{
    const float* x    = (const float*)d_in[0];
    const float* fcos = (const float*)d_in[1];
    const float* fsin = (const float*)d_in[2];
    const float* mask = (const float*)d_in[3];
    const float* Wqkv = (const float*)d_in[4];
    const float* bqkv = (const float*)d_in[5];
    const float* proj = (const float*)d_in[6];
    const float* Wout = (const float*)d_in[7];
    const float* bout = (const float*)d_in[8];
    float* out = (float*)d_out;

    // Workspace (floats), 13,714,432 fl = 54.86 MB (proven size):
    float* R0 = (float*)d_ws;          // KV-half fp32 [2048][2048] / q fp32 [4096][1024]
    float* R1 = R0 + 4194304;          // x hi+lo bf16 / ctx hi+lo bf16
    float* R2 = R1 + 4194304;          // weights hi/lo (persistent, transposed)
    float* R3 = R2 + 4194304;          // partials [16][16][4160] = 1,064,960
    float* R4 = R3 + 1064960;          // kvsum [16][4160] = 66,560

    unsigned short* xh  = (unsigned short*)R1;      // also ctx hi (x dead by then)
    unsigned short* xl  = xh + 4194304;             // also ctx lo
    unsigned short* Wqh = (unsigned short*)R2;      // Wqkv^T hi: [3072][1024]
    unsigned short* Wql = Wqh + 3145728;
    unsigned short* Woh = Wql + 3145728;            // Wout^T hi: [1024][1024]
    unsigned short* Wol = Woh + 1048576;

    // Weight conversions (once per launch), transposed for B-operand K-contiguity
    convert_T_hilo<<<dim3(3072 / 64, 1024 / 64), 256, 0, stream>>>(Wqkv, Wqh, Wql, 1024, 3072);
    convert_T_hilo<<<dim3(1024 / 64, 1024 / 64), 256, 0, stream>>>(Wout, Woh, Wol, 1024, 1024);

    for (int b = 0; b < 4; ++b) {
        const float* xb = x + (size_t)b * 4194304;

        convert_hilo<<<4096, 256, 0, stream>>>(xb, xh, xl, 4194304);

        // K,V in two L-halves; kv partials accumulate across halves
        for (int half = 0; half < 2; ++half) {
            gemm3_kernel<<<dim3(2048 / 64, 2048 / 64), 256, 0, stream>>>(
                xh + (size_t)half * 2048 * 1024, xl + (size_t)half * 2048 * 1024,
                Wqh + (size_t)1024 * 1024, Wql + (size_t)1024 * 1024,
                bqkv + 1024, R0, 1024, 2048);
            kv_mfma_kernel<<<dim3(16, 16), 256, 0, stream>>>(
                R0, fcos + (size_t)half * 2048 * 32, fsin + (size_t)half * 2048 * 32,
                mask + (size_t)b * 4096 + half * 2048, proj, R3, half == 0 ? 1 : 0);
        }
        kv_reduce_kernel<<<dim3(16, 4), 256, 0, stream>>>(R3, R4);

        // Q (full 4096 rows) -> R0
        gemm3_kernel<<<dim3(1024 / 64, 4096 / 64), 256, 0, stream>>>(
            xh, xl, Wqh, Wql, bqkv, R0, 1024, 1024);

        // context + normalization (fused RoPE + proj + relu + hi/lo split on Q)
        context_kernel<<<dim3(64, 16), 256, 0, stream>>>(
            R0, fcos, fsin, proj, R4, xh, xl);

        // out_b = ctx @ Wout + bout
        gemm3_kernel<<<dim3(1024 / 64, 4096 / 64), 256, 0, stream>>>(
            xh, xl, Woh, Wol, bout, out + (size_t)b * 4194304, 1024, 1024);
    }
}

// Round 8
// 850.444 us; speedup vs baseline: 1.1913x; 1.0574x over previous
//
#include <hip/hip_runtime.h>

#define LSEQ   4096
#define EMBED  1024
#define NHEADS 16
#define HDIM   64
#define QKV_N  3072

typedef __attribute__((ext_vector_type(8))) short bf16x8;
typedef __attribute__((ext_vector_type(8))) unsigned short u16x8;
typedef __attribute__((ext_vector_type(4))) float f32x4;
typedef __attribute__((ext_vector_type(16))) float f32x16;

// round-to-nearest-even fp32 -> bf16 (bit pattern), no header dependence
__device__ inline unsigned short bf16_rne(float x) {
    unsigned int u = __float_as_uint(x);
    unsigned int r = (u + 0x7fffu + ((u >> 16) & 1u)) >> 16;
    return (unsigned short)r;
}
__device__ inline float bf16_to_f32(unsigned short h) {
    return __uint_as_float(((unsigned int)h) << 16);
}

// swizzled short-index into a [64 rows][64 shorts] LDS tile:
// 16B chunk c of row r lives at chunk c ^ (r & 7) -> conflict-free b128
// column reads at stride 128B with no padding.
__device__ __forceinline__ int swz64(int row, int s) {
    return row * 64 + ((((s >> 3) ^ (row & 7))) << 3) + (s & 7);
}

// ---------------------------------------------------------------------------
// Convert contiguous fp32 -> hi/lo bf16 arrays. n multiple of 1024.
// ---------------------------------------------------------------------------
__global__ __launch_bounds__(256)
void convert_hilo(const float* __restrict__ in, unsigned short* __restrict__ hi,
                  unsigned short* __restrict__ lo, int n)
{
    int i = (blockIdx.x * 256 + threadIdx.x) << 2;
    if (i >= n) return;
    float4 v = *reinterpret_cast<const float4*>(&in[i]);
    float a[4] = {v.x, v.y, v.z, v.w};
    unsigned short hh[4], ll[4];
    #pragma unroll
    for (int j = 0; j < 4; ++j) {
        hh[j] = bf16_rne(a[j]);
        ll[j] = bf16_rne(a[j] - bf16_to_f32(hh[j]));
    }
    *reinterpret_cast<ushort4*>(&hi[i]) = make_ushort4(hh[0], hh[1], hh[2], hh[3]);
    *reinterpret_cast<ushort4*>(&lo[i]) = make_ushort4(ll[0], ll[1], ll[2], ll[3]);
}

// ---------------------------------------------------------------------------
// Convert fp32 W[K][N] -> TRANSPOSED hi/lo bf16 Wt[N][K] (for B-operand).
// ---------------------------------------------------------------------------
__global__ __launch_bounds__(256)
void convert_T_hilo(const float* __restrict__ in, unsigned short* __restrict__ hi,
                    unsigned short* __restrict__ lo, int K, int N)
{
    __shared__ float tile[64][65];
    const int n0 = blockIdx.x * 64, k0 = blockIdx.y * 64;
    const int t = threadIdx.x;
    #pragma unroll
    for (int i = 0; i < 16; ++i) {
        int idx = t + i * 256;
        int r = idx >> 6, c = idx & 63;
        tile[r][c] = in[(size_t)(k0 + r) * N + n0 + c];
    }
    __syncthreads();
    #pragma unroll
    for (int i = 0; i < 16; ++i) {
        int idx = t + i * 256;
        int r = idx >> 6, c = idx & 63;
        float v = tile[c][r];
        unsigned short h = bf16_rne(v);
        unsigned short l = bf16_rne(v - bf16_to_f32(h));
        size_t o = (size_t)(n0 + r) * K + k0 + c;
        hi[o] = h;
        lo[o] = l;
    }
}

// ---------------------------------------------------------------------------
// bf16x3 split GEMM v5: C = A @ B^T_stored + bias (logical C = A @ B + bias)
// NEW: mfma_f32_32x32x16_bf16 fragments (2x FLOP/instr, +33% FLOP per LDS
// byte, 21% higher MFMA ceiling). 128x64 block tile, 4 waves, each wave owns
// 64x32 (2 row-frags x 1 col-frag). BK=32 (2 k-slices of 16). Dbuf 1-ahead
// prefetch via global_load_lds(16B); XOR swizzle c ^= (row>>1)&3 unchanged
// (source-side pre-swizzle, m173). LDS 48 KB. Grid: (N/64, M/128).
// C/D layout (m74/m101): col=lane&31, row=(reg&3)+8*(reg>>2)+4*(lane>>5).
// ---------------------------------------------------------------------------
__global__ __launch_bounds__(256)
void gemm3_kernel(const unsigned short* __restrict__ Ah, const unsigned short* __restrict__ Al,
                  const unsigned short* __restrict__ Bh, const unsigned short* __restrict__ Bl,
                  const float* __restrict__ bias, float* __restrict__ C,
                  int K, int ldc)
{
    // shorts per buffer: Ah[128][32] @0 (4096), Al @4096, Bh[64][32] @8192
    // (2048), Bl @10240 ; 12288 shorts = 24 KB per buffer, x2 = 48 KB
    __shared__ __align__(16) unsigned short lds[2][12288];

    const int t = threadIdx.x;
    const int wave = t >> 6, lane = t & 63;
    const int wr = wave >> 1, wc = wave & 1;     // wave tile: 64 rows x 32 cols
    const int rowBase = blockIdx.y * 128;
    const int colBase = blockIdx.x * 64;
    const int l31 = lane & 31, kg = lane >> 5;   // 32x32 frag: row/col = l31, k-group = kg

    // staging: wave 0->Ah(8 iss), 1->Al(8), 2->Bh(4), 3->Bl(4); 16B/lane
    const unsigned short* src = (wave == 0) ? Ah : (wave == 1) ? Al : (wave == 2) ? Bh : Bl;
    const int tileRow0 = (wave < 2) ? rowBase : colBase;
    const int ldsOff = (wave < 2) ? wave * 4096 : 8192 + (wave - 2) * 2048;
    const int nIss = (wave < 2) ? 8 : 4;
    const int sRow = lane >> 2;                                  // 0..15
    const int sChunk = (((lane & 3) ^ ((lane >> 3) & 3)) << 3);  // swizzled k-chunk (elems)

    f32x16 acc[2] = {};
    const int NT = K >> 5;

    // prologue: stage tile 0 into buffer 0
    for (int i = 0; i < nIss; ++i) {
        const unsigned short* g = src + (size_t)(tileRow0 + i * 16 + sRow) * K + sChunk;
        __builtin_amdgcn_global_load_lds(
            (const __attribute__((address_space(1))) void*)g,
            (__attribute__((address_space(3))) void*)&lds[0][ldsOff + i * 512], 16, 0, 0);
    }
    __syncthreads();

    for (int tI = 0; tI < NT; ++tI) {
        const int cur = tI & 1;

        // prefetch next K-tile into the other buffer (in flight across MFMA)
        if (tI + 1 < NT) {
            const int k0 = (tI + 1) << 5;
            for (int i = 0; i < nIss; ++i) {
                const unsigned short* g =
                    src + (size_t)(tileRow0 + i * 16 + sRow) * K + k0 + sChunk;
                __builtin_amdgcn_global_load_lds(
                    (const __attribute__((address_space(1))) void*)g,
                    (__attribute__((address_space(3))) void*)&lds[cur ^ 1][ldsOff + i * 512], 16, 0, 0);
            }
        }

        // fragment reads (swizzled): per k-slice ks, chunk index = ks*2 + kg
        bf16x8 ah[2][2], al[2][2], bh[2], bl[2];
        #pragma unroll
        for (int ks = 0; ks < 2; ++ks) {
            #pragma unroll
            for (int m = 0; m < 2; ++m) {
                int r = wr * 64 + m * 32 + l31;
                int off = r * 32 + ((((ks << 1) | kg) ^ ((r >> 1) & 3)) << 3);
                ah[ks][m] = *reinterpret_cast<const bf16x8*>(&lds[cur][off]);
                al[ks][m] = *reinterpret_cast<const bf16x8*>(&lds[cur][4096 + off]);
            }
            int rb = wc * 32 + l31;
            int offb = rb * 32 + ((((ks << 1) | kg) ^ ((rb >> 1) & 3)) << 3);
            bh[ks] = *reinterpret_cast<const bf16x8*>(&lds[cur][8192 + offb]);
            bl[ks] = *reinterpret_cast<const bf16x8*>(&lds[cur][10240 + offb]);
        }
        #pragma unroll
        for (int ks = 0; ks < 2; ++ks)
            #pragma unroll
            for (int m = 0; m < 2; ++m) {
                acc[m] = __builtin_amdgcn_mfma_f32_32x32x16_bf16(ah[ks][m], bh[ks], acc[m], 0, 0, 0);
                acc[m] = __builtin_amdgcn_mfma_f32_32x32x16_bf16(ah[ks][m], bl[ks], acc[m], 0, 0, 0);
                acc[m] = __builtin_amdgcn_mfma_f32_32x32x16_bf16(al[ks][m], bh[ks], acc[m], 0, 0, 0);
            }

        __syncthreads();  // drains this iter's prefetch (overlapped with MFMA above)
    }

    // epilogue: 32x32 C/D mapping col=lane&31, row=(reg&3)+8*(reg>>2)+4*kg
    const int col = colBase + wc * 32 + l31;
    const float bv = bias[col];
    #pragma unroll
    for (int m = 0; m < 2; ++m) {
        #pragma unroll
        for (int reg = 0; reg < 16; ++reg) {
            int row = rowBase + wr * 64 + m * 32 + (reg & 3) + 8 * (reg >> 2) + 4 * kg;
            C[(size_t)row * ldc + col] = acc[m][reg] + bv;
        }
    }
}

// ---------------------------------------------------------------------------
// kv MFMA kernel (unchanged from R7): per (chunk of 128 L-rows, head) per half.
// ---------------------------------------------------------------------------
__global__ __launch_bounds__(256)
void kv_mfma_kernel(const float* __restrict__ kvb, const float* __restrict__ cosb,
                    const float* __restrict__ sinb, const float* __restrict__ maskb,
                    const float* __restrict__ proj, float* __restrict__ partial,
                    int first)
{
    __shared__ __align__(16) char smem[66816];
    unsigned short* KR_h  = (unsigned short*)smem;
    unsigned short* KR_l  = (unsigned short*)(smem + 8192);
    float*          PS    = (float*)smem;                    // aliases KR (fp32 [64][64])
    unsigned short* PJT_h = (unsigned short*)(smem + 16384);
    unsigned short* PJT_l = (unsigned short*)(smem + 24576);
    unsigned short* KPT_h = (unsigned short*)(smem + 32768);
    unsigned short* KPT_l = (unsigned short*)(smem + 40960);
    unsigned short* VT_h  = (unsigned short*)(smem + 49152);
    unsigned short* VT_l  = (unsigned short*)(smem + 57344);
    float*          MS    = (float*)(smem + 65536);
    float*          KS    = (float*)(smem + 65792);

    const int chunk = blockIdx.x;   // 0..15 (128 rows each)
    const int hh    = blockIdx.y;   // 0..15
    const int t = threadIdx.x;
    const int w = t >> 6, lane = t & 63;
    const int fr = lane & 15, fq = lane >> 4;

    {
        int r = t >> 2, c0 = (t & 3) << 4;
        #pragma unroll
        for (int k = 0; k < 4; ++k)
            *reinterpret_cast<float4*>(&PS[r * 64 + c0 + k * 4]) =
                *reinterpret_cast<const float4*>(&proj[(size_t)hh * 4096 + r * 64 + c0 + k * 4]);
    }
    __syncthreads();
    {
        int m = t >> 2, d0 = (t & 3) << 4;
        unsigned short hb[16], lb[16];
        #pragma unroll
        for (int j = 0; j < 16; ++j) {
            float v = PS[(d0 + j) * 64 + m];
            hb[j] = bf16_rne(v);
            lb[j] = bf16_rne(v - bf16_to_f32(hb[j]));
        }
        #pragma unroll
        for (int cp = 0; cp < 2; ++cp) {
            u16x8 vh, vl;
            #pragma unroll
            for (int j = 0; j < 8; ++j) { vh[j] = hb[cp * 8 + j]; vl[j] = lb[cp * 8 + j]; }
            int sidx = swz64(m, d0 + cp * 8);
            *reinterpret_cast<u16x8*>(&PJT_h[sidx]) = vh;
            *reinterpret_cast<u16x8*>(&PJT_l[sidx]) = vl;
        }
    }
    __syncthreads();

    f32x4 acc2[4] = {};
    float ksacc[4] = {0.f, 0.f, 0.f, 0.f};

    for (int sub = 0; sub < 2; ++sub) {
        const int rowL = chunk * 128 + sub * 64;

        float4 vv[4];
        {
            int l = t >> 2, c0 = (t & 3) << 4;
            #pragma unroll
            for (int k2 = 0; k2 < 4; ++k2)
                vv[k2] = *reinterpret_cast<const float4*>(
                    &kvb[(size_t)(rowL + l) * 2048 + 1024 + hh * 64 + c0 + k2 * 4]);
        }
        #pragma unroll
        for (int i = 0; i < 8; ++i) {
            int p = t + (i << 8);
            int l = p >> 5, i2 = p & 31;
            size_t base = (size_t)(rowL + l) * 2048 + hh * 64 + 2 * i2;
            float kr = kvb[base], ki = kvb[base + 1];
            float c = cosb[(size_t)(rowL + l) * 32 + i2];
            float s = sinb[(size_t)(rowL + l) * 32 + i2];
            float xr = kr * c - ki * s;
            float xi = kr * s + ki * c;
            unsigned short h0 = bf16_rne(xr), h1 = bf16_rne(xi);
            unsigned short l0 = bf16_rne(xr - bf16_to_f32(h0));
            unsigned short l1 = bf16_rne(xi - bf16_to_f32(h1));
            int sidx = swz64(l, 2 * i2);
            *reinterpret_cast<unsigned int*>(&KR_h[sidx]) = (unsigned)h0 | ((unsigned)h1 << 16);
            *reinterpret_cast<unsigned int*>(&KR_l[sidx]) = (unsigned)l0 | ((unsigned)l1 << 16);
        }
        if (t < 64) MS[t] = maskb[rowL + t];
        __syncthreads();   // B1

        f32x4 acc1[4] = {};
        #pragma unroll
        for (int ks = 0; ks < 2; ++ks) {
            bf16x8 ah = *reinterpret_cast<const bf16x8*>(&KR_h[swz64(16 * w + fr, ks * 32 + fq * 8)]);
            bf16x8 al = *reinterpret_cast<const bf16x8*>(&KR_l[swz64(16 * w + fr, ks * 32 + fq * 8)]);
            #pragma unroll
            for (int n = 0; n < 4; ++n) {
                bf16x8 bh = *reinterpret_cast<const bf16x8*>(&PJT_h[swz64(16 * n + fr, ks * 32 + fq * 8)]);
                bf16x8 bl = *reinterpret_cast<const bf16x8*>(&PJT_l[swz64(16 * n + fr, ks * 32 + fq * 8)]);
                acc1[n] = __builtin_amdgcn_mfma_f32_16x16x32_bf16(ah, bh, acc1[n], 0, 0, 0);
                acc1[n] = __builtin_amdgcn_mfma_f32_16x16x32_bf16(ah, bl, acc1[n], 0, 0, 0);
                acc1[n] = __builtin_amdgcn_mfma_f32_16x16x32_bf16(al, bh, acc1[n], 0, 0, 0);
            }
        }
        #pragma unroll
        for (int n = 0; n < 4; ++n) {
            unsigned short hb[4], lb[4];
            float ssum = 0.f;
            #pragma unroll
            for (int r = 0; r < 4; ++r) {
                int l = 16 * w + fq * 4 + r;
                float kp = fmaxf(acc1[n][r], 0.f) * MS[l];
                ssum += kp;
                hb[r] = bf16_rne(kp);
                lb[r] = bf16_rne(kp - bf16_to_f32(hb[r]));
            }
            ksacc[n] += ssum;
            int sidx = swz64(16 * n + fr, 16 * w + fq * 4);
            *reinterpret_cast<ushort4*>(&KPT_h[sidx]) = make_ushort4(hb[0], hb[1], hb[2], hb[3]);
            *reinterpret_cast<ushort4*>(&KPT_l[sidx]) = make_ushort4(lb[0], lb[1], lb[2], lb[3]);
        }
        __syncthreads();   // B2

        {
            float* VS = PS;
            int l = t >> 2, c0 = (t & 3) << 4;
            float mv = MS[l];
            #pragma unroll
            for (int k2 = 0; k2 < 4; ++k2) {
                float4 q = vv[k2];
                q.x *= mv; q.y *= mv; q.z *= mv; q.w *= mv;
                *reinterpret_cast<float4*>(&VS[l * 64 + c0 + k2 * 4]) = q;
            }
        }
        __syncthreads();   // B3

        {
            float* VS = PS;
            int d = t >> 2, l0 = (t & 3) << 4;
            unsigned short hb[16], lb[16];
            #pragma unroll
            for (int j = 0; j < 16; ++j) {
                float v = VS[(l0 + j) * 64 + d];
                hb[j] = bf16_rne(v);
                lb[j] = bf16_rne(v - bf16_to_f32(hb[j]));
            }
            #pragma unroll
            for (int cp = 0; cp < 2; ++cp) {
                u16x8 vh, vl;
                #pragma unroll
                for (int j = 0; j < 8; ++j) { vh[j] = hb[cp * 8 + j]; vl[j] = lb[cp * 8 + j]; }
                int sidx = swz64(d, l0 + cp * 8);
                *reinterpret_cast<u16x8*>(&VT_h[sidx]) = vh;
                *reinterpret_cast<u16x8*>(&VT_l[sidx]) = vl;
            }
        }
        __syncthreads();   // B4

        #pragma unroll
        for (int ks = 0; ks < 2; ++ks) {
            bf16x8 ah = *reinterpret_cast<const bf16x8*>(&KPT_h[swz64(16 * w + fr, ks * 32 + fq * 8)]);
            bf16x8 al = *reinterpret_cast<const bf16x8*>(&KPT_l[swz64(16 * w + fr, ks * 32 + fq * 8)]);
            #pragma unroll
            for (int n = 0; n < 4; ++n) {
                bf16x8 bh = *reinterpret_cast<const bf16x8*>(&VT_h[swz64(16 * n + fr, ks * 32 + fq * 8)]);
                bf16x8 bl = *reinterpret_cast<const bf16x8*>(&VT_l[swz64(16 * n + fr, ks * 32 + fq * 8)]);
                acc2[n] = __builtin_amdgcn_mfma_f32_16x16x32_bf16(ah, bh, acc2[n], 0, 0, 0);
                acc2[n] = __builtin_amdgcn_mfma_f32_16x16x32_bf16(ah, bl, acc2[n], 0, 0, 0);
                acc2[n] = __builtin_amdgcn_mfma_f32_16x16x32_bf16(al, bh, acc2[n], 0, 0, 0);
            }
        }
    }

    #pragma unroll
    for (int n = 0; n < 4; ++n) {
        float v = ksacc[n];
        v += __shfl_xor(v, 16);
        v += __shfl_xor(v, 32);
        if (fq == 0) KS[w * 64 + 16 * n + fr] = v;
    }
    __syncthreads();

    float* dst = partial + ((size_t)hh * 16 + chunk) * 4160;
    #pragma unroll
    for (int n = 0; n < 4; ++n)
        #pragma unroll
        for (int r = 0; r < 4; ++r) {
            int m = 16 * w + fq * 4 + r;
            int d = 16 * n + fr;
            if (first) dst[m * 64 + d] = acc2[n][r];
            else       dst[m * 64 + d] += acc2[n][r];
        }
    if (t < 64) {
        float s = KS[t] + KS[64 + t] + KS[128 + t] + KS[192 + t];
        if (first) dst[4096 + t] = s;
        else       dst[4096 + t] += s;
    }
}

// Reduce 16 chunk partials -> kv (64x64) + ksum (64) per head. grid (16,4).
__global__ __launch_bounds__(256)
void kv_reduce_kernel(const float* __restrict__ partial, float* __restrict__ kvout)
{
    const int h = blockIdx.x;
    const int seg = blockIdx.y;
    for (int idx = seg * 1040 + threadIdx.x; idx < (seg + 1) * 1040; idx += 256) {
        float s = 0.f;
        for (int c = 0; c < 16; ++c)
            s += partial[((size_t)h * 16 + c) * 4160 + idx];
        kvout[(size_t)h * 4160 + idx] = s;
    }
}

// ---------------------------------------------------------------------------
// context per (h, 64-row L tile) for ONE batch (unchanged).
// ---------------------------------------------------------------------------
__global__ __launch_bounds__(256)
void context_kernel(const float* __restrict__ qb, const float* __restrict__ cosb,
                    const float* __restrict__ sinb, const float* __restrict__ proj,
                    const float* __restrict__ kvsum, unsigned short* __restrict__ ch,
                    unsigned short* __restrict__ cl)
{
    const int lt = blockIdx.x;   // 0..63
    const int h  = blockIdx.y;   // 0..15
    const int t = threadIdx.x;

    __shared__ float bufA[64][68];
    __shared__ float qp[64][68];
    __shared__ float pj[64][64];
    __shared__ float ksum[64];

    for (int i = t; i < 1024; i += 256)
        *reinterpret_cast<float4*>(&pj[0][0] + (size_t)i * 4) =
            *reinterpret_cast<const float4*>(proj + (size_t)h * 4096 + (size_t)i * 4);
    if (t < 64) ksum[t] = kvsum[(size_t)h * 4160 + 4096 + t];

    const int rowL = lt * 64;
    #pragma unroll
    for (int i = 0; i < 8; ++i) {
        int p = t + i * 256;
        int l = p >> 5, i2 = p & 31;
        size_t base = (size_t)(rowL + l) * 1024 + h * HDIM + 2 * i2;
        float qr = qb[base], qi = qb[base + 1];
        float c = cosb[(size_t)(rowL + l) * 32 + i2];
        float s = sinb[(size_t)(rowL + l) * 32 + i2];
        bufA[l][2 * i2]     = qr * c - qi * s;
        bufA[l][2 * i2 + 1] = qr * s + qi * c;
    }
    __syncthreads();

    {
        int l = t >> 2, m0 = (t & 3) << 4;
        float a[16] = {};
        for (int d = 0; d < 64; ++d) {
            float ql = bufA[l][d];
            const float* pr = &pj[d][m0];
            #pragma unroll
            for (int j = 0; j < 16; ++j) a[j] = fmaf(ql, pr[j], a[j]);
        }
        #pragma unroll
        for (int j = 0; j < 16; ++j) qp[l][m0 + j] = fmaxf(a[j], 0.f);
    }
    __syncthreads();

    #pragma unroll
    for (int i = 0; i < 4; ++i) {
        int idx = t + i * 256;
        int mm = idx >> 4, dd = (idx & 15) << 2;
        *reinterpret_cast<float4*>(&bufA[mm][dd]) =
            *reinterpret_cast<const float4*>(&kvsum[(size_t)h * 4160 + mm * 64 + dd]);
    }
    __syncthreads();

    {
        int l = t >> 2, d0 = (t & 3) << 4;
        float a[16] = {};
        float nrm = 0.f;
        for (int mm = 0; mm < 64; ++mm) {
            float qv = qp[l][mm];
            nrm = fmaf(qv, ksum[mm], nrm);
            const float* kr = &bufA[mm][d0];
            #pragma unroll
            for (int j = 0; j < 16; ++j) a[j] = fmaf(qv, kr[j], a[j]);
        }
        float inv = 1.0f / (nrm + 1e-4f);
        size_t orow = (size_t)(rowL + l) * 1024 + h * HDIM + d0;
        #pragma unroll
        for (int j4 = 0; j4 < 4; ++j4) {
            unsigned short hh[4], ll[4];
            #pragma unroll
            for (int j = 0; j < 4; ++j) {
                float v = a[j4 * 4 + j] * inv;
                hh[j] = bf16_rne(v);
                ll[j] = bf16_rne(v - bf16_to_f32(hh[j]));
            }
            *reinterpret_cast<ushort4*>(&ch[orow + j4 * 4]) = make_ushort4(hh[0], hh[1], hh[2], hh[3]);
            *reinterpret_cast<ushort4*>(&cl[orow + j4 * 4]) = make_ushort4(ll[0], ll[1], ll[2], ll[3]);
        }
    }
}

extern "C" void kernel_launch(void* const* d_in, const int* in_sizes, int n_in,
                              void* d_out, int out_size, void* d_ws, size_t ws_size,
                              hipStream_t stream)
{
    const float* x    = (const float*)d_in[0];
    const float* fcos = (const float*)d_in[1];
    const float* fsin = (const float*)d_in[2];
    const float* mask = (const float*)d_in[3];
    const float* Wqkv = (const float*)d_in[4];
    const float* bqkv = (const float*)d_in[5];
    const float* proj = (const float*)d_in[6];
    const float* Wout = (const float*)d_in[7];
    const float* bout = (const float*)d_in[8];
    float* out = (float*)d_out;

    // Workspace (floats), 13,714,432 fl = 54.86 MB (proven size):
    float* R0 = (float*)d_ws;          // KV-half fp32 [2048][2048] / q fp32 [4096][1024]
    float* R1 = R0 + 4194304;          // x hi+lo bf16 / ctx hi+lo bf16
    float* R2 = R1 + 4194304;          // weights hi/lo (persistent, transposed)
    float* R3 = R2 + 4194304;          // partials [16][16][4160] = 1,064,960
    float* R4 = R3 + 1064960;          // kvsum [16][4160] = 66,560

    unsigned short* xh  = (unsigned short*)R1;      // also ctx hi (x dead by then)
    unsigned short* xl  = xh + 4194304;             // also ctx lo
    unsigned short* Wqh = (unsigned short*)R2;      // Wqkv^T hi: [3072][1024]
    unsigned short* Wql = Wqh + 3145728;
    unsigned short* Woh = Wql + 3145728;            // Wout^T hi: [1024][1024]
    unsigned short* Wol = Woh + 1048576;

    // Weight conversions (once per launch), transposed for B-operand K-contiguity
    convert_T_hilo<<<dim3(3072 / 64, 1024 / 64), 256, 0, stream>>>(Wqkv, Wqh, Wql, 1024, 3072);
    convert_T_hilo<<<dim3(1024 / 64, 1024 / 64), 256, 0, stream>>>(Wout, Woh, Wol, 1024, 1024);

    for (int b = 0; b < 4; ++b) {
        const float* xb = x + (size_t)b * 4194304;

        convert_hilo<<<4096, 256, 0, stream>>>(xb, xh, xl, 4194304);

        // K,V in two L-halves; kv partials accumulate across halves
        for (int half = 0; half < 2; ++half) {
            gemm3_kernel<<<dim3(2048 / 64, 2048 / 128), 256, 0, stream>>>(
                xh + (size_t)half * 2048 * 1024, xl + (size_t)half * 2048 * 1024,
                Wqh + (size_t)1024 * 1024, Wql + (size_t)1024 * 1024,
                bqkv + 1024, R0, 1024, 2048);
            kv_mfma_kernel<<<dim3(16, 16), 256, 0, stream>>>(
                R0, fcos + (size_t)half * 2048 * 32, fsin + (size_t)half * 2048 * 32,
                mask + (size_t)b * 4096 + half * 2048, proj, R3, half == 0 ? 1 : 0);
        }
        kv_reduce_kernel<<<dim3(16, 4), 256, 0, stream>>>(R3, R4);

        // Q (full 4096 rows) -> R0
        gemm3_kernel<<<dim3(1024 / 64, 4096 / 128), 256, 0, stream>>>(
            xh, xl, Wqh, Wql, bqkv, R0, 1024, 1024);

        // context + normalization (fused RoPE + proj + relu + hi/lo split on Q)
        context_kernel<<<dim3(64, 16), 256, 0, stream>>>(
            R0, fcos, fsin, proj, R4, xh, xl);

        // out_b = ctx @ Wout + bout
        gemm3_kernel<<<dim3(1024 / 64, 4096 / 128), 256, 0, stream>>>(
            xh, xl, Woh, Wol, bout, out + (size_t)b * 4194304, 1024, 1024);
    }
}

// Round 9
// 613.569 us; speedup vs baseline: 1.6512x; 1.3861x over previous
//
#include <hip/hip_runtime.h>

#define LSEQ   4096
#define ROWS   16384             // 4 batches x 4096
#define EMBED  1024
#define NHEADS 16
#define HDIM   64
#define QKV_N  3072

typedef __attribute__((ext_vector_type(8))) short bf16x8;
typedef __attribute__((ext_vector_type(8))) unsigned short u16x8;
typedef __attribute__((ext_vector_type(4))) float f32x4;
typedef __attribute__((ext_vector_type(16))) float f32x16;

// round-to-nearest-even fp32 -> bf16 (bit pattern), no header dependence
__device__ inline unsigned short bf16_rne(float x) {
    unsigned int u = __float_as_uint(x);
    unsigned int r = (u + 0x7fffu + ((u >> 16) & 1u)) >> 16;
    return (unsigned short)r;
}
__device__ inline float bf16_to_f32(unsigned short h) {
    return __uint_as_float(((unsigned int)h) << 16);
}

// swizzled short-index into a [64 rows][64 shorts] LDS tile (kv kernel)
__device__ __forceinline__ int swz64(int row, int s) {
    return row * 64 + ((((s >> 3) ^ (row & 7))) << 3) + (s & 7);
}

// ---------------------------------------------------------------------------
// Convert contiguous fp32 -> hi/lo bf16 arrays. n multiple of 1024.
// ---------------------------------------------------------------------------
__global__ __launch_bounds__(256)
void convert_hilo(const float* __restrict__ in, unsigned short* __restrict__ hi,
                  unsigned short* __restrict__ lo, int n)
{
    int i = (blockIdx.x * 256 + threadIdx.x) << 2;
    if (i >= n) return;
    float4 v = *reinterpret_cast<const float4*>(&in[i]);
    float a[4] = {v.x, v.y, v.z, v.w};
    unsigned short hh[4], ll[4];
    #pragma unroll
    for (int j = 0; j < 4; ++j) {
        hh[j] = bf16_rne(a[j]);
        ll[j] = bf16_rne(a[j] - bf16_to_f32(hh[j]));
    }
    *reinterpret_cast<ushort4*>(&hi[i]) = make_ushort4(hh[0], hh[1], hh[2], hh[3]);
    *reinterpret_cast<ushort4*>(&lo[i]) = make_ushort4(ll[0], ll[1], ll[2], ll[3]);
}

// ---------------------------------------------------------------------------
// Convert fp32 W[K][N] -> TRANSPOSED hi/lo bf16 Wt[N][K] (for B-operand).
// ---------------------------------------------------------------------------
__global__ __launch_bounds__(256)
void convert_T_hilo(const float* __restrict__ in, unsigned short* __restrict__ hi,
                    unsigned short* __restrict__ lo, int K, int N)
{
    __shared__ float tile[64][65];
    const int n0 = blockIdx.x * 64, k0 = blockIdx.y * 64;
    const int t = threadIdx.x;
    #pragma unroll
    for (int i = 0; i < 16; ++i) {
        int idx = t + i * 256;
        int r = idx >> 6, c = idx & 63;
        tile[r][c] = in[(size_t)(k0 + r) * N + n0 + c];
    }
    __syncthreads();
    #pragma unroll
    for (int i = 0; i < 16; ++i) {
        int idx = t + i * 256;
        int r = idx >> 6, c = idx & 63;
        float v = tile[c][r];
        unsigned short h = bf16_rne(v);
        unsigned short l = bf16_rne(v - bf16_to_f32(h));
        size_t o = (size_t)(n0 + r) * K + k0 + c;
        hi[o] = h;
        lo[o] = l;
    }
}

// ---------------------------------------------------------------------------
// bf16x3 split GEMM v6: C = A @ B^T_stored + bias (logical C = A @ B + bias)
// 128x128 block tile, 4 waves (2x2), each wave owns 64x64 = 2x2 frags of
// mfma_f32_32x32x16_bf16. BK=32. Reads/MFMA = 16/24 = 0.67 (was 1.0).
// Dbuf 1-ahead prefetch via global_load_lds(16B); XOR-swizzled k-chunks
// (c ^= (row>>1)&3) on pre-swizzled source addr + frag reads. LDS 64 KB,
// 2 blocks/CU. M,N multiples of 128; K multiple of 32.
// C/D layout (m74/m101): col=lane&31, row=(reg&3)+8*(reg>>2)+4*(lane>>5).
// ---------------------------------------------------------------------------
__global__ __launch_bounds__(256)
void gemm3_kernel(const unsigned short* __restrict__ Ah, const unsigned short* __restrict__ Al,
                  const unsigned short* __restrict__ Bh, const unsigned short* __restrict__ Bl,
                  const float* __restrict__ bias, float* __restrict__ C,
                  int K, int ldc)
{
    // shorts per buffer: Ah[128][32] @0, Al @4096, Bh[128][32] @8192, Bl @12288
    __shared__ __align__(16) unsigned short lds[2][16384];   // 64 KB

    const int t = threadIdx.x;
    const int wave = t >> 6, lane = t & 63;
    const int wr = wave >> 1, wc = wave & 1;     // wave tile: 64 rows x 64 cols
    const int rowBase = blockIdx.y * 128;
    const int colBase = blockIdx.x * 128;
    const int l31 = lane & 31, kg = lane >> 5;

    // staging: wave w stages tile w (Ah/Al/Bh/Bl), 8 issues x 64 lanes x 16B
    const unsigned short* src = (wave == 0) ? Ah : (wave == 1) ? Al : (wave == 2) ? Bh : Bl;
    const int tileRow0 = (wave < 2) ? rowBase : colBase;
    const int ldsOff = wave * 4096;
    const int sRow = lane >> 2;                                  // 0..15
    const int sChunk = (((lane & 3) ^ ((lane >> 3) & 3)) << 3);  // swizzled k-chunk (elems)

    f32x16 acc[2][2] = {};
    const int NT = K >> 5;

    // prologue: stage tile 0 into buffer 0
    #pragma unroll
    for (int i = 0; i < 8; ++i) {
        const unsigned short* g = src + (size_t)(tileRow0 + i * 16 + sRow) * K + sChunk;
        __builtin_amdgcn_global_load_lds(
            (const __attribute__((address_space(1))) void*)g,
            (__attribute__((address_space(3))) void*)&lds[0][ldsOff + i * 512], 16, 0, 0);
    }
    __syncthreads();

    for (int tI = 0; tI < NT; ++tI) {
        const int cur = tI & 1;

        // prefetch next K-tile into the other buffer (in flight across MFMA)
        if (tI + 1 < NT) {
            const int k0 = (tI + 1) << 5;
            #pragma unroll
            for (int i = 0; i < 8; ++i) {
                const unsigned short* g =
                    src + (size_t)(tileRow0 + i * 16 + sRow) * K + k0 + sChunk;
                __builtin_amdgcn_global_load_lds(
                    (const __attribute__((address_space(1))) void*)g,
                    (__attribute__((address_space(3))) void*)&lds[cur ^ 1][ldsOff + i * 512], 16, 0, 0);
            }
        }

        // fragment reads (swizzled): per k-slice ks, chunk index = ks*2 + kg
        bf16x8 ah[2][2], al[2][2], bh[2][2], bl[2][2];
        #pragma unroll
        for (int ks = 0; ks < 2; ++ks) {
            #pragma unroll
            for (int m = 0; m < 2; ++m) {
                int r = wr * 64 + m * 32 + l31;
                int off = r * 32 + ((((ks << 1) | kg) ^ ((r >> 1) & 3)) << 3);
                ah[ks][m] = *reinterpret_cast<const bf16x8*>(&lds[cur][off]);
                al[ks][m] = *reinterpret_cast<const bf16x8*>(&lds[cur][4096 + off]);
            }
            #pragma unroll
            for (int n = 0; n < 2; ++n) {
                int rb = wc * 64 + n * 32 + l31;
                int off = rb * 32 + ((((ks << 1) | kg) ^ ((rb >> 1) & 3)) << 3);
                bh[ks][n] = *reinterpret_cast<const bf16x8*>(&lds[cur][8192 + off]);
                bl[ks][n] = *reinterpret_cast<const bf16x8*>(&lds[cur][12288 + off]);
            }
        }
        #pragma unroll
        for (int ks = 0; ks < 2; ++ks)
            #pragma unroll
            for (int m = 0; m < 2; ++m)
                #pragma unroll
                for (int n = 0; n < 2; ++n) {
                    acc[m][n] = __builtin_amdgcn_mfma_f32_32x32x16_bf16(ah[ks][m], bh[ks][n], acc[m][n], 0, 0, 0);
                    acc[m][n] = __builtin_amdgcn_mfma_f32_32x32x16_bf16(ah[ks][m], bl[ks][n], acc[m][n], 0, 0, 0);
                    acc[m][n] = __builtin_amdgcn_mfma_f32_32x32x16_bf16(al[ks][m], bh[ks][n], acc[m][n], 0, 0, 0);
                }

        __syncthreads();  // drains this iter's prefetch (overlapped with MFMA above)
    }

    // epilogue: 32x32 C/D mapping col=lane&31, row=(reg&3)+8*(reg>>2)+4*kg
    #pragma unroll
    for (int n = 0; n < 2; ++n) {
        const int col = colBase + wc * 64 + n * 32 + l31;
        const float bv = bias[col];
        #pragma unroll
        for (int m = 0; m < 2; ++m) {
            #pragma unroll
            for (int reg = 0; reg < 16; ++reg) {
                int row = rowBase + wr * 64 + m * 32 + (reg & 3) + 8 * (reg >> 2) + 4 * kg;
                C[(size_t)row * ldc + col] = acc[m][n][reg] + bv;
            }
        }
    }
}

// ---------------------------------------------------------------------------
// kv MFMA kernel, full-batch: per (chunk of 256 rows, head). grid (64, 16).
// kvb: [16384][2048] fp32 (k at col h*64, v at col 1024+h*64). Chunks never
// straddle batches (256 | 4096). cos/sin indexed (row & 4095), mask [16384].
// partial layout: [h][64 chunks][4160] (4096 = kv [m][d], +64 = ksum).
// ---------------------------------------------------------------------------
__global__ __launch_bounds__(256)
void kv_mfma_kernel(const float* __restrict__ kvb, const float* __restrict__ cosb,
                    const float* __restrict__ sinb, const float* __restrict__ maskb,
                    const float* __restrict__ proj, float* __restrict__ partial)
{
    __shared__ __align__(16) char smem[66816];
    unsigned short* KR_h  = (unsigned short*)smem;
    unsigned short* KR_l  = (unsigned short*)(smem + 8192);
    float*          PS    = (float*)smem;                    // aliases KR (fp32 [64][64])
    unsigned short* PJT_h = (unsigned short*)(smem + 16384);
    unsigned short* PJT_l = (unsigned short*)(smem + 24576);
    unsigned short* KPT_h = (unsigned short*)(smem + 32768);
    unsigned short* KPT_l = (unsigned short*)(smem + 40960);
    unsigned short* VT_h  = (unsigned short*)(smem + 49152);
    unsigned short* VT_l  = (unsigned short*)(smem + 57344);
    float*          MS    = (float*)(smem + 65536);
    float*          KS    = (float*)(smem + 65792);

    const int chunk = blockIdx.x;   // 0..63 (256 rows each)
    const int hh    = blockIdx.y;   // 0..15
    const int t = threadIdx.x;
    const int w = t >> 6, lane = t & 63;
    const int fr = lane & 15, fq = lane >> 4;

    {
        int r = t >> 2, c0 = (t & 3) << 4;
        #pragma unroll
        for (int k = 0; k < 4; ++k)
            *reinterpret_cast<float4*>(&PS[r * 64 + c0 + k * 4]) =
                *reinterpret_cast<const float4*>(&proj[(size_t)hh * 4096 + r * 64 + c0 + k * 4]);
    }
    __syncthreads();
    {
        int m = t >> 2, d0 = (t & 3) << 4;
        unsigned short hb[16], lb[16];
        #pragma unroll
        for (int j = 0; j < 16; ++j) {
            float v = PS[(d0 + j) * 64 + m];
            hb[j] = bf16_rne(v);
            lb[j] = bf16_rne(v - bf16_to_f32(hb[j]));
        }
        #pragma unroll
        for (int cp = 0; cp < 2; ++cp) {
            u16x8 vh, vl;
            #pragma unroll
            for (int j = 0; j < 8; ++j) { vh[j] = hb[cp * 8 + j]; vl[j] = lb[cp * 8 + j]; }
            int sidx = swz64(m, d0 + cp * 8);
            *reinterpret_cast<u16x8*>(&PJT_h[sidx]) = vh;
            *reinterpret_cast<u16x8*>(&PJT_l[sidx]) = vl;
        }
    }
    __syncthreads();

    f32x4 acc2[4] = {};
    float ksacc[4] = {0.f, 0.f, 0.f, 0.f};

    for (int sub = 0; sub < 4; ++sub) {
        const int rowL = chunk * 256 + sub * 64;   // global row

        float4 vv[4];
        {
            int l = t >> 2, c0 = (t & 3) << 4;
            #pragma unroll
            for (int k2 = 0; k2 < 4; ++k2)
                vv[k2] = *reinterpret_cast<const float4*>(
                    &kvb[(size_t)(rowL + l) * 2048 + 1024 + hh * 64 + c0 + k2 * 4]);
        }
        #pragma unroll
        for (int i = 0; i < 8; ++i) {
            int p = t + (i << 8);
            int l = p >> 5, i2 = p & 31;
            size_t base = (size_t)(rowL + l) * 2048 + hh * 64 + 2 * i2;
            float kr = kvb[base], ki = kvb[base + 1];
            int crow = (rowL + l) & 4095;
            float c = cosb[(size_t)crow * 32 + i2];
            float s = sinb[(size_t)crow * 32 + i2];
            float xr = kr * c - ki * s;
            float xi = kr * s + ki * c;
            unsigned short h0 = bf16_rne(xr), h1 = bf16_rne(xi);
            unsigned short l0 = bf16_rne(xr - bf16_to_f32(h0));
            unsigned short l1 = bf16_rne(xi - bf16_to_f32(h1));
            int sidx = swz64(l, 2 * i2);
            *reinterpret_cast<unsigned int*>(&KR_h[sidx]) = (unsigned)h0 | ((unsigned)h1 << 16);
            *reinterpret_cast<unsigned int*>(&KR_l[sidx]) = (unsigned)l0 | ((unsigned)l1 << 16);
        }
        if (t < 64) MS[t] = maskb[rowL + t];
        __syncthreads();   // B1

        f32x4 acc1[4] = {};
        #pragma unroll
        for (int ks = 0; ks < 2; ++ks) {
            bf16x8 ah = *reinterpret_cast<const bf16x8*>(&KR_h[swz64(16 * w + fr, ks * 32 + fq * 8)]);
            bf16x8 al = *reinterpret_cast<const bf16x8*>(&KR_l[swz64(16 * w + fr, ks * 32 + fq * 8)]);
            #pragma unroll
            for (int n = 0; n < 4; ++n) {
                bf16x8 bh = *reinterpret_cast<const bf16x8*>(&PJT_h[swz64(16 * n + fr, ks * 32 + fq * 8)]);
                bf16x8 bl = *reinterpret_cast<const bf16x8*>(&PJT_l[swz64(16 * n + fr, ks * 32 + fq * 8)]);
                acc1[n] = __builtin_amdgcn_mfma_f32_16x16x32_bf16(ah, bh, acc1[n], 0, 0, 0);
                acc1[n] = __builtin_amdgcn_mfma_f32_16x16x32_bf16(ah, bl, acc1[n], 0, 0, 0);
                acc1[n] = __builtin_amdgcn_mfma_f32_16x16x32_bf16(al, bh, acc1[n], 0, 0, 0);
            }
        }
        #pragma unroll
        for (int n = 0; n < 4; ++n) {
            unsigned short hb[4], lb[4];
            float ssum = 0.f;
            #pragma unroll
            for (int r = 0; r < 4; ++r) {
                int l = 16 * w + fq * 4 + r;
                float kp = fmaxf(acc1[n][r], 0.f) * MS[l];
                ssum += kp;
                hb[r] = bf16_rne(kp);
                lb[r] = bf16_rne(kp - bf16_to_f32(hb[r]));
            }
            ksacc[n] += ssum;
            int sidx = swz64(16 * n + fr, 16 * w + fq * 4);
            *reinterpret_cast<ushort4*>(&KPT_h[sidx]) = make_ushort4(hb[0], hb[1], hb[2], hb[3]);
            *reinterpret_cast<ushort4*>(&KPT_l[sidx]) = make_ushort4(lb[0], lb[1], lb[2], lb[3]);
        }
        __syncthreads();   // B2

        {
            float* VS = PS;
            int l = t >> 2, c0 = (t & 3) << 4;
            float mv = MS[l];
            #pragma unroll
            for (int k2 = 0; k2 < 4; ++k2) {
                float4 q = vv[k2];
                q.x *= mv; q.y *= mv; q.z *= mv; q.w *= mv;
                *reinterpret_cast<float4*>(&VS[l * 64 + c0 + k2 * 4]) = q;
            }
        }
        __syncthreads();   // B3

        {
            float* VS = PS;
            int d = t >> 2, l0 = (t & 3) << 4;
            unsigned short hb[16], lb[16];
            #pragma unroll
            for (int j = 0; j < 16; ++j) {
                float v = VS[(l0 + j) * 64 + d];
                hb[j] = bf16_rne(v);
                lb[j] = bf16_rne(v - bf16_to_f32(hb[j]));
            }
            #pragma unroll
            for (int cp = 0; cp < 2; ++cp) {
                u16x8 vh, vl;
                #pragma unroll
                for (int j = 0; j < 8; ++j) { vh[j] = hb[cp * 8 + j]; vl[j] = lb[cp * 8 + j]; }
                int sidx = swz64(d, l0 + cp * 8);
                *reinterpret_cast<u16x8*>(&VT_h[sidx]) = vh;
                *reinterpret_cast<u16x8*>(&VT_l[sidx]) = vl;
            }
        }
        __syncthreads();   // B4

        #pragma unroll
        for (int ks = 0; ks < 2; ++ks) {
            bf16x8 ah = *reinterpret_cast<const bf16x8*>(&KPT_h[swz64(16 * w + fr, ks * 32 + fq * 8)]);
            bf16x8 al = *reinterpret_cast<const bf16x8*>(&KPT_l[swz64(16 * w + fr, ks * 32 + fq * 8)]);
            #pragma unroll
            for (int n = 0; n < 4; ++n) {
                bf16x8 bh = *reinterpret_cast<const bf16x8*>(&VT_h[swz64(16 * n + fr, ks * 32 + fq * 8)]);
                bf16x8 bl = *reinterpret_cast<const bf16x8*>(&VT_l[swz64(16 * n + fr, ks * 32 + fq * 8)]);
                acc2[n] = __builtin_amdgcn_mfma_f32_16x16x32_bf16(ah, bh, acc2[n], 0, 0, 0);
                acc2[n] = __builtin_amdgcn_mfma_f32_16x16x32_bf16(ah, bl, acc2[n], 0, 0, 0);
                acc2[n] = __builtin_amdgcn_mfma_f32_16x16x32_bf16(al, bh, acc2[n], 0, 0, 0);
            }
        }
    }

    #pragma unroll
    for (int n = 0; n < 4; ++n) {
        float v = ksacc[n];
        v += __shfl_xor(v, 16);
        v += __shfl_xor(v, 32);
        if (fq == 0) KS[w * 64 + 16 * n + fr] = v;
    }
    __syncthreads();

    float* dst = partial + ((size_t)hh * 64 + chunk) * 4160;
    #pragma unroll
    for (int n = 0; n < 4; ++n)
        #pragma unroll
        for (int r = 0; r < 4; ++r) {
            int m = 16 * w + fq * 4 + r;
            int d = 16 * n + fr;
            dst[m * 64 + d] = acc2[n][r];
        }
    if (t < 64)
        dst[4096 + t] = KS[t] + KS[64 + t] + KS[128 + t] + KS[192 + t];
}

// Reduce 16 per-batch chunk partials -> kv (64x64) + ksum (64) per (b,h).
// grid (64, 4): blockIdx.x = b*16+h. partial: [h][64 chunks][4160].
__global__ __launch_bounds__(256)
void kv_reduce_kernel(const float* __restrict__ partial, float* __restrict__ kvout)
{
    const int bh = blockIdx.x;          // b*16 + h
    const int b = bh >> 4, h = bh & 15;
    const int seg = blockIdx.y;         // 4160 = 4 segments x 1040
    for (int idx = seg * 1040 + threadIdx.x; idx < (seg + 1) * 1040; idx += 256) {
        float s = 0.f;
        for (int c = 0; c < 16; ++c)
            s += partial[((size_t)h * 64 + b * 16 + c) * 4160 + idx];
        kvout[(size_t)bh * 4160 + idx] = s;
    }
}

// ---------------------------------------------------------------------------
// context, full-batch: grid (256, 16). qb: [16384][1024] (q at col h*64).
// batch = lt>>6; cos/sin at (row & 4095). Writes ctx as hi/lo bf16.
// ---------------------------------------------------------------------------
__global__ __launch_bounds__(256)
void context_kernel(const float* __restrict__ qb, const float* __restrict__ cosb,
                    const float* __restrict__ sinb, const float* __restrict__ proj,
                    const float* __restrict__ kvsum, unsigned short* __restrict__ ch,
                    unsigned short* __restrict__ cl)
{
    const int lt = blockIdx.x;   // 0..255
    const int h  = blockIdx.y;   // 0..15
    const int t = threadIdx.x;
    const int bh = (lt >> 6) * 16 + h;

    __shared__ float bufA[64][68];
    __shared__ float qp[64][68];
    __shared__ float pj[64][64];
    __shared__ float ksum[64];

    for (int i = t; i < 1024; i += 256)
        *reinterpret_cast<float4*>(&pj[0][0] + (size_t)i * 4) =
            *reinterpret_cast<const float4*>(proj + (size_t)h * 4096 + (size_t)i * 4);
    if (t < 64) ksum[t] = kvsum[(size_t)bh * 4160 + 4096 + t];

    const int rowL = lt * 64;            // global row
    #pragma unroll
    for (int i = 0; i < 8; ++i) {
        int p = t + i * 256;
        int l = p >> 5, i2 = p & 31;
        size_t base = (size_t)(rowL + l) * 1024 + h * HDIM + 2 * i2;
        float qr = qb[base], qi = qb[base + 1];
        int crow = (rowL + l) & 4095;
        float c = cosb[(size_t)crow * 32 + i2];
        float s = sinb[(size_t)crow * 32 + i2];
        bufA[l][2 * i2]     = qr * c - qi * s;
        bufA[l][2 * i2 + 1] = qr * s + qi * c;
    }
    __syncthreads();

    {
        int l = t >> 2, m0 = (t & 3) << 4;
        float a[16] = {};
        for (int d = 0; d < 64; ++d) {
            float ql = bufA[l][d];
            const float* pr = &pj[d][m0];
            #pragma unroll
            for (int j = 0; j < 16; ++j) a[j] = fmaf(ql, pr[j], a[j]);
        }
        #pragma unroll
        for (int j = 0; j < 16; ++j) qp[l][m0 + j] = fmaxf(a[j], 0.f);
    }
    __syncthreads();

    #pragma unroll
    for (int i = 0; i < 4; ++i) {
        int idx = t + i * 256;
        int mm = idx >> 4, dd = (idx & 15) << 2;
        *reinterpret_cast<float4*>(&bufA[mm][dd]) =
            *reinterpret_cast<const float4*>(&kvsum[(size_t)bh * 4160 + mm * 64 + dd]);
    }
    __syncthreads();

    {
        int l = t >> 2, d0 = (t & 3) << 4;
        float a[16] = {};
        float nrm = 0.f;
        for (int mm = 0; mm < 64; ++mm) {
            float qv = qp[l][mm];
            nrm = fmaf(qv, ksum[mm], nrm);
            const float* kr = &bufA[mm][d0];
            #pragma unroll
            for (int j = 0; j < 16; ++j) a[j] = fmaf(qv, kr[j], a[j]);
        }
        float inv = 1.0f / (nrm + 1e-4f);
        size_t orow = (size_t)(rowL + l) * 1024 + h * HDIM + d0;
        #pragma unroll
        for (int j4 = 0; j4 < 4; ++j4) {
            unsigned short hh2[4], ll2[4];
            #pragma unroll
            for (int j = 0; j < 4; ++j) {
                float v = a[j4 * 4 + j] * inv;
                hh2[j] = bf16_rne(v);
                ll2[j] = bf16_rne(v - bf16_to_f32(hh2[j]));
            }
            *reinterpret_cast<ushort4*>(&ch[orow + j4 * 4]) = make_ushort4(hh2[0], hh2[1], hh2[2], hh2[3]);
            *reinterpret_cast<ushort4*>(&cl[orow + j4 * 4]) = make_ushort4(ll2[0], ll2[1], ll2[2], ll2[3]);
        }
    }
}

extern "C" void kernel_launch(void* const* d_in, const int* in_sizes, int n_in,
                              void* d_out, int out_size, void* d_ws, size_t ws_size,
                              hipStream_t stream)
{
    const float* x    = (const float*)d_in[0];
    const float* fcos = (const float*)d_in[1];
    const float* fsin = (const float*)d_in[2];
    const float* mask = (const float*)d_in[3];
    const float* Wqkv = (const float*)d_in[4];
    const float* bqkv = (const float*)d_in[5];
    const float* proj = (const float*)d_in[6];
    const float* Wout = (const float*)d_in[7];
    const float* bout = (const float*)d_in[8];
    float* out = (float*)d_out;

    // Workspace (floats), 59,052,032 fl = 236.2 MB (ws = 256 MiB per the
    // fillBuffer WRITE_SIZE evidence; R1's 287 MB crash bounds it above).
    float* W    = (float*)d_ws;          //  4,194,304 fl: weights hi/lo (transposed)
    float* XHL  = W + 4194304;           // 16,777,216 fl: x hi+lo bf16 -> later ctx hi+lo
    float* KVQ  = XHL + 16777216;        // 33,554,432 fl: KV fp32 [16384][2048] -> later Q [16384][1024]
    float* PART = KVQ + 33554432;        //  4,259,840 fl: partials [16][64][4160]
    float* KSUM = PART + 4259840;        //    266,240 fl: kvsum [64][4160]

    unsigned short* Wqh = (unsigned short*)W;       // Wqkv^T hi: [3072][1024]
    unsigned short* Wql = Wqh + 3145728;
    unsigned short* Woh = Wql + 3145728;            // Wout^T hi: [1024][1024]
    unsigned short* Wol = Woh + 1048576;
    unsigned short* xh  = (unsigned short*)XHL;     // also ctx hi (x dead by then)
    unsigned short* xl  = xh + 16777216;            // also ctx lo

    // Weight conversions (once per launch), transposed for B-operand K-contiguity
    convert_T_hilo<<<dim3(3072 / 64, 1024 / 64), 256, 0, stream>>>(Wqkv, Wqh, Wql, 1024, 3072);
    convert_T_hilo<<<dim3(1024 / 64, 1024 / 64), 256, 0, stream>>>(Wout, Woh, Wol, 1024, 1024);

    // x -> hi/lo, full batch
    convert_hilo<<<16384, 256, 0, stream>>>(x, xh, xl, ROWS * EMBED);

    // K,V = x @ Wqkv[:,1024:3072] + bqkv[1024:]  (full batch, [16384][2048])
    gemm3_kernel<<<dim3(2048 / 128, ROWS / 128), 256, 0, stream>>>(
        xh, xl, Wqh + (size_t)1024 * 1024, Wql + (size_t)1024 * 1024,
        bqkv + 1024, KVQ, 1024, 2048);

    // fused RoPE+proj+relu+mask -> kv partials (full batch)
    kv_mfma_kernel<<<dim3(64, 16), 256, 0, stream>>>(KVQ, fcos, fsin, mask, proj, PART);

    // reduce partials -> kv/ksum per (b,h)
    kv_reduce_kernel<<<dim3(64, 4), 256, 0, stream>>>(PART, KSUM);

    // Q = x @ Wqkv[:,0:1024] + bqkv[0:1024]  (overwrites KV region; KV dead)
    gemm3_kernel<<<dim3(1024 / 128, ROWS / 128), 256, 0, stream>>>(
        xh, xl, Wqh, Wql, bqkv, KVQ, 1024, 1024);

    // context + normalization; writes ctx hi/lo over xh/xl (x dead)
    context_kernel<<<dim3(256, 16), 256, 0, stream>>>(
        KVQ, fcos, fsin, proj, KSUM, xh, xl);

    // out = ctx @ Wout + bout
    gemm3_kernel<<<dim3(1024 / 128, ROWS / 128), 256, 0, stream>>>(
        xh, xl, Woh, Wol, bout, out, 1024, 1024);
}

// Round 10
// 550.668 us; speedup vs baseline: 1.8399x; 1.1142x over previous
//
#include <hip/hip_runtime.h>

#define LSEQ   4096
#define ROWS   16384             // 4 batches x 4096
#define EMBED  1024
#define NHEADS 16
#define HDIM   64
#define QKV_N  3072

typedef __attribute__((ext_vector_type(8))) short bf16x8;
typedef __attribute__((ext_vector_type(8))) unsigned short u16x8;
typedef __attribute__((ext_vector_type(4))) float f32x4;
typedef __attribute__((ext_vector_type(16))) float f32x16;

// round-to-nearest-even fp32 -> bf16 (bit pattern), no header dependence
__device__ inline unsigned short bf16_rne(float x) {
    unsigned int u = __float_as_uint(x);
    unsigned int r = (u + 0x7fffu + ((u >> 16) & 1u)) >> 16;
    return (unsigned short)r;
}
__device__ inline float bf16_to_f32(unsigned short h) {
    return __uint_as_float(((unsigned int)h) << 16);
}

// swizzled short-index into a [64 rows][64 shorts] LDS tile (kv kernel)
__device__ __forceinline__ int swz64(int row, int s) {
    return row * 64 + ((((s >> 3) ^ (row & 7))) << 3) + (s & 7);
}

// ---------------------------------------------------------------------------
// Convert contiguous fp32 -> hi/lo bf16 arrays. n multiple of 1024.
// ---------------------------------------------------------------------------
__global__ __launch_bounds__(256)
void convert_hilo(const float* __restrict__ in, unsigned short* __restrict__ hi,
                  unsigned short* __restrict__ lo, int n)
{
    int i = (blockIdx.x * 256 + threadIdx.x) << 2;
    if (i >= n) return;
    float4 v = *reinterpret_cast<const float4*>(&in[i]);
    float a[4] = {v.x, v.y, v.z, v.w};
    unsigned short hh[4], ll[4];
    #pragma unroll
    for (int j = 0; j < 4; ++j) {
        hh[j] = bf16_rne(a[j]);
        ll[j] = bf16_rne(a[j] - bf16_to_f32(hh[j]));
    }
    *reinterpret_cast<ushort4*>(&hi[i]) = make_ushort4(hh[0], hh[1], hh[2], hh[3]);
    *reinterpret_cast<ushort4*>(&lo[i]) = make_ushort4(ll[0], ll[1], ll[2], ll[3]);
}

// ---------------------------------------------------------------------------
// Convert fp32 W[K][N] -> TRANSPOSED hi/lo bf16 Wt[N][K] (for B-operand).
// ---------------------------------------------------------------------------
__global__ __launch_bounds__(256)
void convert_T_hilo(const float* __restrict__ in, unsigned short* __restrict__ hi,
                    unsigned short* __restrict__ lo, int K, int N)
{
    __shared__ float tile[64][65];
    const int n0 = blockIdx.x * 64, k0 = blockIdx.y * 64;
    const int t = threadIdx.x;
    #pragma unroll
    for (int i = 0; i < 16; ++i) {
        int idx = t + i * 256;
        int r = idx >> 6, c = idx & 63;
        tile[r][c] = in[(size_t)(k0 + r) * N + n0 + c];
    }
    __syncthreads();
    #pragma unroll
    for (int i = 0; i < 16; ++i) {
        int idx = t + i * 256;
        int r = idx >> 6, c = idx & 63;
        float v = tile[c][r];
        unsigned short h = bf16_rne(v);
        unsigned short l = bf16_rne(v - bf16_to_f32(h));
        size_t o = (size_t)(n0 + r) * K + k0 + c;
        hi[o] = h;
        lo[o] = l;
    }
}

// ---------------------------------------------------------------------------
// bf16x3 split GEMM v7: C = A @ B^T_stored + bias (logical C = A @ B + bias)
// Block 256x256, 8 waves (2M x 4N), per-wave 128x64 = 4x2 frags of
// mfma_f32_32x32x16_bf16 (read:MFMA = 24:48, +33% FLOP/LDS-byte vs v6).
// LDS tiles interleave hi|lo in one [rows][64-short] (128B) row: chunk c of
// row r holds global chunk g = c ^ (r&7); g<4 -> hi chunk g, g>=4 -> lo
// chunk g-4. 128B rows start at bank 0, 8-position XOR spreads a wave64
// b128 frag read to exactly 8 accesses/bank = conflict floor (conflict-free).
// Staging: global_load_lds(16B), LDS-linear dest, per-lane source selects
// xh/xl by swizzled chunk. Dbuf 1-ahead prefetch. LDS 128 KB, 1 block/CU,
// 2 waves/SIMD. M,N multiples of 256; K multiple of 32.
// C/D layout (m74/m101): col=lane&31, row=(reg&3)+8*(reg>>2)+4*(lane>>5).
// ---------------------------------------------------------------------------
__global__ __launch_bounds__(512)
void gemm3_kernel(const unsigned short* __restrict__ Ah, const unsigned short* __restrict__ Al,
                  const unsigned short* __restrict__ Bh, const unsigned short* __restrict__ Bl,
                  const float* __restrict__ bias, float* __restrict__ C,
                  int K, int ldc)
{
    // shorts per buffer: A [256][64] @0 (16384), B [256][64] @16384
    __shared__ __align__(16) unsigned short lds[2][32768];   // 128 KB

    const int t = threadIdx.x;
    const int wave = t >> 6, lane = t & 63;
    const int wr = wave >> 2, wc = wave & 3;     // wave tile: 128 rows x 64 cols
    const int rowBase = blockIdx.y * 256;
    const int colBase = blockIdx.x * 256;
    const int l31 = lane & 31, kg = lane >> 5;
    const int r7 = l31 & 7;                      // frag-read row swizzle key

    // staging: waves 0-3 stage A (64 rows each), 4-7 stage B. 8 issues/wave.
    const int sIsA = (wave < 4) ? 1 : 0;
    const int lr = lane >> 3;                    // row within 8-row issue group
    const int lc = lane & 7;                     // LDS chunk position
    const int g  = lc ^ lr;                      // swizzled global chunk
    const unsigned short* sSrc = sIsA ? (g < 4 ? Ah : Al) : (g < 4 ? Bh : Bl);
    const int gk = (g & 3) << 3;                 // k-offset (shorts) within step
    const int tRow0 = (sIsA ? rowBase : colBase) + (wave & 3) * 64;
    const int ldsOff = (sIsA ? 0 : 16384) + (wave & 3) * 4096;

    f32x16 acc[4][2] = {};
    const int NT = K >> 5;

    // prologue: stage tile 0 into buffer 0
    #pragma unroll
    for (int i = 0; i < 8; ++i) {
        const unsigned short* gp = sSrc + (size_t)(tRow0 + i * 8 + lr) * K + gk;
        __builtin_amdgcn_global_load_lds(
            (const __attribute__((address_space(1))) void*)gp,
            (__attribute__((address_space(3))) void*)&lds[0][ldsOff + i * 512], 16, 0, 0);
    }
    __syncthreads();

    for (int tI = 0; tI < NT; ++tI) {
        const int cur = tI & 1;

        // prefetch next K-tile into the other buffer (in flight across MFMA)
        if (tI + 1 < NT) {
            const int k0 = (tI + 1) << 5;
            #pragma unroll
            for (int i = 0; i < 8; ++i) {
                const unsigned short* gp = sSrc + (size_t)(tRow0 + i * 8 + lr) * K + k0 + gk;
                __builtin_amdgcn_global_load_lds(
                    (const __attribute__((address_space(1))) void*)gp,
                    (__attribute__((address_space(3))) void*)&lds[cur ^ 1][ldsOff + i * 512], 16, 0, 0);
            }
        }

        // per k-slice: frag reads (8-pos XOR swizzle) + MFMA
        #pragma unroll
        for (int ks = 0; ks < 2; ++ks) {
            const int gh = ks * 2 + kg;          // hi global chunk 0..3
            bf16x8 ah[4], al[4], bh[2], bl[2];
            #pragma unroll
            for (int m = 0; m < 4; ++m) {
                int r = wr * 128 + m * 32 + l31;
                ah[m] = *reinterpret_cast<const bf16x8*>(&lds[cur][r * 64 + ((gh ^ r7) << 3)]);
                al[m] = *reinterpret_cast<const bf16x8*>(&lds[cur][r * 64 + (((gh + 4) ^ r7) << 3)]);
            }
            #pragma unroll
            for (int n = 0; n < 2; ++n) {
                int rb = wc * 64 + n * 32 + l31;
                bh[n] = *reinterpret_cast<const bf16x8*>(&lds[cur][16384 + rb * 64 + ((gh ^ r7) << 3)]);
                bl[n] = *reinterpret_cast<const bf16x8*>(&lds[cur][16384 + rb * 64 + (((gh + 4) ^ r7) << 3)]);
            }
            #pragma unroll
            for (int m = 0; m < 4; ++m)
                #pragma unroll
                for (int n = 0; n < 2; ++n) {
                    acc[m][n] = __builtin_amdgcn_mfma_f32_32x32x16_bf16(ah[m], bh[n], acc[m][n], 0, 0, 0);
                    acc[m][n] = __builtin_amdgcn_mfma_f32_32x32x16_bf16(ah[m], bl[n], acc[m][n], 0, 0, 0);
                    acc[m][n] = __builtin_amdgcn_mfma_f32_32x32x16_bf16(al[m], bh[n], acc[m][n], 0, 0, 0);
                }
        }

        __syncthreads();  // drains this iter's prefetch (overlapped with MFMA above)
    }

    // epilogue: 32x32 C/D mapping col=lane&31, row=(reg&3)+8*(reg>>2)+4*kg
    #pragma unroll
    for (int n = 0; n < 2; ++n) {
        const int col = colBase + wc * 64 + n * 32 + l31;
        const float bv = bias[col];
        #pragma unroll
        for (int m = 0; m < 4; ++m) {
            #pragma unroll
            for (int reg = 0; reg < 16; ++reg) {
                int row = rowBase + wr * 128 + m * 32 + (reg & 3) + 8 * (reg >> 2) + 4 * kg;
                C[(size_t)row * ldc + col] = acc[m][n][reg] + bv;
            }
        }
    }
}

// ---------------------------------------------------------------------------
// kv MFMA kernel, full-batch (unchanged from R9): per (256-row chunk, head).
// ---------------------------------------------------------------------------
__global__ __launch_bounds__(256)
void kv_mfma_kernel(const float* __restrict__ kvb, const float* __restrict__ cosb,
                    const float* __restrict__ sinb, const float* __restrict__ maskb,
                    const float* __restrict__ proj, float* __restrict__ partial)
{
    __shared__ __align__(16) char smem[66816];
    unsigned short* KR_h  = (unsigned short*)smem;
    unsigned short* KR_l  = (unsigned short*)(smem + 8192);
    float*          PS    = (float*)smem;                    // aliases KR (fp32 [64][64])
    unsigned short* PJT_h = (unsigned short*)(smem + 16384);
    unsigned short* PJT_l = (unsigned short*)(smem + 24576);
    unsigned short* KPT_h = (unsigned short*)(smem + 32768);
    unsigned short* KPT_l = (unsigned short*)(smem + 40960);
    unsigned short* VT_h  = (unsigned short*)(smem + 49152);
    unsigned short* VT_l  = (unsigned short*)(smem + 57344);
    float*          MS    = (float*)(smem + 65536);
    float*          KS    = (float*)(smem + 65792);

    const int chunk = blockIdx.x;   // 0..63 (256 rows each)
    const int hh    = blockIdx.y;   // 0..15
    const int t = threadIdx.x;
    const int w = t >> 6, lane = t & 63;
    const int fr = lane & 15, fq = lane >> 4;

    {
        int r = t >> 2, c0 = (t & 3) << 4;
        #pragma unroll
        for (int k = 0; k < 4; ++k)
            *reinterpret_cast<float4*>(&PS[r * 64 + c0 + k * 4]) =
                *reinterpret_cast<const float4*>(&proj[(size_t)hh * 4096 + r * 64 + c0 + k * 4]);
    }
    __syncthreads();
    {
        int m = t >> 2, d0 = (t & 3) << 4;
        unsigned short hb[16], lb[16];
        #pragma unroll
        for (int j = 0; j < 16; ++j) {
            float v = PS[(d0 + j) * 64 + m];
            hb[j] = bf16_rne(v);
            lb[j] = bf16_rne(v - bf16_to_f32(hb[j]));
        }
        #pragma unroll
        for (int cp = 0; cp < 2; ++cp) {
            u16x8 vh, vl;
            #pragma unroll
            for (int j = 0; j < 8; ++j) { vh[j] = hb[cp * 8 + j]; vl[j] = lb[cp * 8 + j]; }
            int sidx = swz64(m, d0 + cp * 8);
            *reinterpret_cast<u16x8*>(&PJT_h[sidx]) = vh;
            *reinterpret_cast<u16x8*>(&PJT_l[sidx]) = vl;
        }
    }
    __syncthreads();

    f32x4 acc2[4] = {};
    float ksacc[4] = {0.f, 0.f, 0.f, 0.f};

    for (int sub = 0; sub < 4; ++sub) {
        const int rowL = chunk * 256 + sub * 64;   // global row

        float4 vv[4];
        {
            int l = t >> 2, c0 = (t & 3) << 4;
            #pragma unroll
            for (int k2 = 0; k2 < 4; ++k2)
                vv[k2] = *reinterpret_cast<const float4*>(
                    &kvb[(size_t)(rowL + l) * 2048 + 1024 + hh * 64 + c0 + k2 * 4]);
        }
        #pragma unroll
        for (int i = 0; i < 8; ++i) {
            int p = t + (i << 8);
            int l = p >> 5, i2 = p & 31;
            size_t base = (size_t)(rowL + l) * 2048 + hh * 64 + 2 * i2;
            float kr = kvb[base], ki = kvb[base + 1];
            int crow = (rowL + l) & 4095;
            float c = cosb[(size_t)crow * 32 + i2];
            float s = sinb[(size_t)crow * 32 + i2];
            float xr = kr * c - ki * s;
            float xi = kr * s + ki * c;
            unsigned short h0 = bf16_rne(xr), h1 = bf16_rne(xi);
            unsigned short l0 = bf16_rne(xr - bf16_to_f32(h0));
            unsigned short l1 = bf16_rne(xi - bf16_to_f32(h1));
            int sidx = swz64(l, 2 * i2);
            *reinterpret_cast<unsigned int*>(&KR_h[sidx]) = (unsigned)h0 | ((unsigned)h1 << 16);
            *reinterpret_cast<unsigned int*>(&KR_l[sidx]) = (unsigned)l0 | ((unsigned)l1 << 16);
        }
        if (t < 64) MS[t] = maskb[rowL + t];
        __syncthreads();   // B1

        f32x4 acc1[4] = {};
        #pragma unroll
        for (int ks = 0; ks < 2; ++ks) {
            bf16x8 ah = *reinterpret_cast<const bf16x8*>(&KR_h[swz64(16 * w + fr, ks * 32 + fq * 8)]);
            bf16x8 al = *reinterpret_cast<const bf16x8*>(&KR_l[swz64(16 * w + fr, ks * 32 + fq * 8)]);
            #pragma unroll
            for (int n = 0; n < 4; ++n) {
                bf16x8 bh = *reinterpret_cast<const bf16x8*>(&PJT_h[swz64(16 * n + fr, ks * 32 + fq * 8)]);
                bf16x8 bl = *reinterpret_cast<const bf16x8*>(&PJT_l[swz64(16 * n + fr, ks * 32 + fq * 8)]);
                acc1[n] = __builtin_amdgcn_mfma_f32_16x16x32_bf16(ah, bh, acc1[n], 0, 0, 0);
                acc1[n] = __builtin_amdgcn_mfma_f32_16x16x32_bf16(ah, bl, acc1[n], 0, 0, 0);
                acc1[n] = __builtin_amdgcn_mfma_f32_16x16x32_bf16(al, bh, acc1[n], 0, 0, 0);
            }
        }
        #pragma unroll
        for (int n = 0; n < 4; ++n) {
            unsigned short hb[4], lb[4];
            float ssum = 0.f;
            #pragma unroll
            for (int r = 0; r < 4; ++r) {
                int l = 16 * w + fq * 4 + r;
                float kp = fmaxf(acc1[n][r], 0.f) * MS[l];
                ssum += kp;
                hb[r] = bf16_rne(kp);
                lb[r] = bf16_rne(kp - bf16_to_f32(hb[r]));
            }
            ksacc[n] += ssum;
            int sidx = swz64(16 * n + fr, 16 * w + fq * 4);
            *reinterpret_cast<ushort4*>(&KPT_h[sidx]) = make_ushort4(hb[0], hb[1], hb[2], hb[3]);
            *reinterpret_cast<ushort4*>(&KPT_l[sidx]) = make_ushort4(lb[0], lb[1], lb[2], lb[3]);
        }
        __syncthreads();   // B2

        {
            float* VS = PS;
            int l = t >> 2, c0 = (t & 3) << 4;
            float mv = MS[l];
            #pragma unroll
            for (int k2 = 0; k2 < 4; ++k2) {
                float4 q = vv[k2];
                q.x *= mv; q.y *= mv; q.z *= mv; q.w *= mv;
                *reinterpret_cast<float4*>(&VS[l * 64 + c0 + k2 * 4]) = q;
            }
        }
        __syncthreads();   // B3

        {
            float* VS = PS;
            int d = t >> 2, l0 = (t & 3) << 4;
            unsigned short hb[16], lb[16];
            #pragma unroll
            for (int j = 0; j < 16; ++j) {
                float v = VS[(l0 + j) * 64 + d];
                hb[j] = bf16_rne(v);
                lb[j] = bf16_rne(v - bf16_to_f32(hb[j]));
            }
            #pragma unroll
            for (int cp = 0; cp < 2; ++cp) {
                u16x8 vh, vl;
                #pragma unroll
                for (int j = 0; j < 8; ++j) { vh[j] = hb[cp * 8 + j]; vl[j] = lb[cp * 8 + j]; }
                int sidx = swz64(d, l0 + cp * 8);
                *reinterpret_cast<u16x8*>(&VT_h[sidx]) = vh;
                *reinterpret_cast<u16x8*>(&VT_l[sidx]) = vl;
            }
        }
        __syncthreads();   // B4

        #pragma unroll
        for (int ks = 0; ks < 2; ++ks) {
            bf16x8 ah = *reinterpret_cast<const bf16x8*>(&KPT_h[swz64(16 * w + fr, ks * 32 + fq * 8)]);
            bf16x8 al = *reinterpret_cast<const bf16x8*>(&KPT_l[swz64(16 * w + fr, ks * 32 + fq * 8)]);
            #pragma unroll
            for (int n = 0; n < 4; ++n) {
                bf16x8 bh = *reinterpret_cast<const bf16x8*>(&VT_h[swz64(16 * n + fr, ks * 32 + fq * 8)]);
                bf16x8 bl = *reinterpret_cast<const bf16x8*>(&VT_l[swz64(16 * n + fr, ks * 32 + fq * 8)]);
                acc2[n] = __builtin_amdgcn_mfma_f32_16x16x32_bf16(ah, bh, acc2[n], 0, 0, 0);
                acc2[n] = __builtin_amdgcn_mfma_f32_16x16x32_bf16(ah, bl, acc2[n], 0, 0, 0);
                acc2[n] = __builtin_amdgcn_mfma_f32_16x16x32_bf16(al, bh, acc2[n], 0, 0, 0);
            }
        }
    }

    #pragma unroll
    for (int n = 0; n < 4; ++n) {
        float v = ksacc[n];
        v += __shfl_xor(v, 16);
        v += __shfl_xor(v, 32);
        if (fq == 0) KS[w * 64 + 16 * n + fr] = v;
    }
    __syncthreads();

    float* dst = partial + ((size_t)hh * 64 + chunk) * 4160;
    #pragma unroll
    for (int n = 0; n < 4; ++n)
        #pragma unroll
        for (int r = 0; r < 4; ++r) {
            int m = 16 * w + fq * 4 + r;
            int d = 16 * n + fr;
            dst[m * 64 + d] = acc2[n][r];
        }
    if (t < 64)
        dst[4096 + t] = KS[t] + KS[64 + t] + KS[128 + t] + KS[192 + t];
}

// Reduce 16 per-batch chunk partials -> kv (64x64) + ksum (64) per (b,h).
__global__ __launch_bounds__(256)
void kv_reduce_kernel(const float* __restrict__ partial, float* __restrict__ kvout)
{
    const int bh = blockIdx.x;          // b*16 + h
    const int b = bh >> 4, h = bh & 15;
    const int seg = blockIdx.y;         // 4160 = 4 segments x 1040
    for (int idx = seg * 1040 + threadIdx.x; idx < (seg + 1) * 1040; idx += 256) {
        float s = 0.f;
        for (int c = 0; c < 16; ++c)
            s += partial[((size_t)h * 64 + b * 16 + c) * 4160 + idx];
        kvout[(size_t)bh * 4160 + idx] = s;
    }
}

// ---------------------------------------------------------------------------
// context, full-batch (unchanged from R9): grid (256, 16).
// ---------------------------------------------------------------------------
__global__ __launch_bounds__(256)
void context_kernel(const float* __restrict__ qb, const float* __restrict__ cosb,
                    const float* __restrict__ sinb, const float* __restrict__ proj,
                    const float* __restrict__ kvsum, unsigned short* __restrict__ ch,
                    unsigned short* __restrict__ cl)
{
    const int lt = blockIdx.x;   // 0..255
    const int h  = blockIdx.y;   // 0..15
    const int t = threadIdx.x;
    const int bh = (lt >> 6) * 16 + h;

    __shared__ float bufA[64][68];
    __shared__ float qp[64][68];
    __shared__ float pj[64][64];
    __shared__ float ksum[64];

    for (int i = t; i < 1024; i += 256)
        *reinterpret_cast<float4*>(&pj[0][0] + (size_t)i * 4) =
            *reinterpret_cast<const float4*>(proj + (size_t)h * 4096 + (size_t)i * 4);
    if (t < 64) ksum[t] = kvsum[(size_t)bh * 4160 + 4096 + t];

    const int rowL = lt * 64;            // global row
    #pragma unroll
    for (int i = 0; i < 8; ++i) {
        int p = t + i * 256;
        int l = p >> 5, i2 = p & 31;
        size_t base = (size_t)(rowL + l) * 1024 + h * HDIM + 2 * i2;
        float qr = qb[base], qi = qb[base + 1];
        int crow = (rowL + l) & 4095;
        float c = cosb[(size_t)crow * 32 + i2];
        float s = sinb[(size_t)crow * 32 + i2];
        bufA[l][2 * i2]     = qr * c - qi * s;
        bufA[l][2 * i2 + 1] = qr * s + qi * c;
    }
    __syncthreads();

    {
        int l = t >> 2, m0 = (t & 3) << 4;
        float a[16] = {};
        for (int d = 0; d < 64; ++d) {
            float ql = bufA[l][d];
            const float* pr = &pj[d][m0];
            #pragma unroll
            for (int j = 0; j < 16; ++j) a[j] = fmaf(ql, pr[j], a[j]);
        }
        #pragma unroll
        for (int j = 0; j < 16; ++j) qp[l][m0 + j] = fmaxf(a[j], 0.f);
    }
    __syncthreads();

    #pragma unroll
    for (int i = 0; i < 4; ++i) {
        int idx = t + i * 256;
        int mm = idx >> 4, dd = (idx & 15) << 2;
        *reinterpret_cast<float4*>(&bufA[mm][dd]) =
            *reinterpret_cast<const float4*>(&kvsum[(size_t)bh * 4160 + mm * 64 + dd]);
    }
    __syncthreads();

    {
        int l = t >> 2, d0 = (t & 3) << 4;
        float a[16] = {};
        float nrm = 0.f;
        for (int mm = 0; mm < 64; ++mm) {
            float qv = qp[l][mm];
            nrm = fmaf(qv, ksum[mm], nrm);
            const float* kr = &bufA[mm][d0];
            #pragma unroll
            for (int j = 0; j < 16; ++j) a[j] = fmaf(qv, kr[j], a[j]);
        }
        float inv = 1.0f / (nrm + 1e-4f);
        size_t orow = (size_t)(rowL + l) * 1024 + h * HDIM + d0;
        #pragma unroll
        for (int j4 = 0; j4 < 4; ++j4) {
            unsigned short hh2[4], ll2[4];
            #pragma unroll
            for (int j = 0; j < 4; ++j) {
                float v = a[j4 * 4 + j] * inv;
                hh2[j] = bf16_rne(v);
                ll2[j] = bf16_rne(v - bf16_to_f32(hh2[j]));
            }
            *reinterpret_cast<ushort4*>(&ch[orow + j4 * 4]) = make_ushort4(hh2[0], hh2[1], hh2[2], hh2[3]);
            *reinterpret_cast<ushort4*>(&cl[orow + j4 * 4]) = make_ushort4(ll2[0], ll2[1], ll2[2], ll2[3]);
        }
    }
}

extern "C" void kernel_launch(void* const* d_in, const int* in_sizes, int n_in,
                              void* d_out, int out_size, void* d_ws, size_t ws_size,
                              hipStream_t stream)
{
    const float* x    = (const float*)d_in[0];
    const float* fcos = (const float*)d_in[1];
    const float* fsin = (const float*)d_in[2];
    const float* mask = (const float*)d_in[3];
    const float* Wqkv = (const float*)d_in[4];
    const float* bqkv = (const float*)d_in[5];
    const float* proj = (const float*)d_in[6];
    const float* Wout = (const float*)d_in[7];
    const float* bout = (const float*)d_in[8];
    float* out = (float*)d_out;

    // Workspace (floats), 59,052,032 fl = 236.2 MB (< 256 MiB ws).
    float* W    = (float*)d_ws;          //  4,194,304 fl: weights hi/lo (transposed)
    float* XHL  = W + 4194304;           // 16,777,216 fl: x hi+lo bf16 -> later ctx hi+lo
    float* KVQ  = XHL + 16777216;        // 33,554,432 fl: KV fp32 [16384][2048] -> later Q [16384][1024]
    float* PART = KVQ + 33554432;        //  4,259,840 fl: partials [16][64][4160]
    float* KSUM = PART + 4259840;        //    266,240 fl: kvsum [64][4160]

    unsigned short* Wqh = (unsigned short*)W;       // Wqkv^T hi: [3072][1024]
    unsigned short* Wql = Wqh + 3145728;
    unsigned short* Woh = Wql + 3145728;            // Wout^T hi: [1024][1024]
    unsigned short* Wol = Woh + 1048576;
    unsigned short* xh  = (unsigned short*)XHL;     // also ctx hi (x dead by then)
    unsigned short* xl  = xh + 16777216;            // also ctx lo

    // Weight conversions (once per launch), transposed for B-operand K-contiguity
    convert_T_hilo<<<dim3(3072 / 64, 1024 / 64), 256, 0, stream>>>(Wqkv, Wqh, Wql, 1024, 3072);
    convert_T_hilo<<<dim3(1024 / 64, 1024 / 64), 256, 0, stream>>>(Wout, Woh, Wol, 1024, 1024);

    // x -> hi/lo, full batch
    convert_hilo<<<16384, 256, 0, stream>>>(x, xh, xl, ROWS * EMBED);

    // K,V = x @ Wqkv[:,1024:3072] + bqkv[1024:]  (full batch, [16384][2048])
    gemm3_kernel<<<dim3(2048 / 256, ROWS / 256), 512, 0, stream>>>(
        xh, xl, Wqh + (size_t)1024 * 1024, Wql + (size_t)1024 * 1024,
        bqkv + 1024, KVQ, 1024, 2048);

    // fused RoPE+proj+relu+mask -> kv partials (full batch)
    kv_mfma_kernel<<<dim3(64, 16), 256, 0, stream>>>(KVQ, fcos, fsin, mask, proj, PART);

    // reduce partials -> kv/ksum per (b,h)
    kv_reduce_kernel<<<dim3(64, 4), 256, 0, stream>>>(PART, KSUM);

    // Q = x @ Wqkv[:,0:1024] + bqkv[0:1024]  (overwrites KV region; KV dead)
    gemm3_kernel<<<dim3(1024 / 256, ROWS / 256), 512, 0, stream>>>(
        xh, xl, Wqh, Wql, bqkv, KVQ, 1024, 1024);

    // context + normalization; writes ctx hi/lo over xh/xl (x dead)
    context_kernel<<<dim3(256, 16), 256, 0, stream>>>(
        KVQ, fcos, fsin, proj, KSUM, xh, xl);

    // out = ctx @ Wout + bout
    gemm3_kernel<<<dim3(1024 / 256, ROWS / 256), 512, 0, stream>>>(
        xh, xl, Woh, Wol, bout, out, 1024, 1024);
}